// Round 8
// baseline (1455.218 us; speedup 1.0000x reference)
//
#include <hip/hip_runtime.h>
#include <stdint.h>

// EVGNN backbone on MI355X.
// L1: fully fused conv kernel — edge gather (EPG=8), butterfly reduce,
// per-wave LDS Z row, inline [27][16] GEMM + bias + ReLU (W staged per block).
// R7 fix: W staging must loop (432 entries > 256 threads); R6 left
// WL[256..431] uninitialized -> absmax 0.099 fail.
// L2/L3: CSR gather -> Z -> tiled GEMM. L4/L5: skinny GEMM.
// CSR build: bucketed two-level counting sort (write-amp ~1 vs 16x atomic).
// Pooling: pool1 balanced gather; pools 2-4 strip kernel (skew-proof).

__device__ __forceinline__ float fclamp01(float v) { return fminf(fmaxf(v, 0.f), 1.f); }

// ---------------- simple CSR build (small layers) ----------------
__global__ __launch_bounds__(256) void k_count(const int* __restrict__ dst, int E,
                                               int* __restrict__ cnt) {
  int e = blockIdx.x * 256 + threadIdx.x;
  if (e < E) atomicAdd(&cnt[dst[e]], 1);
}

__global__ __launch_bounds__(1024) void k_scan1(const int* __restrict__ cnt, int V,
                                                int* __restrict__ rowptr,
                                                int* __restrict__ bsum) {
  __shared__ int sm[1024];
  int i = blockIdx.x * 1024 + threadIdx.x;
  int v = (i < V) ? cnt[i] : 0;
  sm[threadIdx.x] = v;
  __syncthreads();
  for (int off = 1; off < 1024; off <<= 1) {
    int t = (threadIdx.x >= off) ? sm[threadIdx.x - off] : 0;
    __syncthreads();
    sm[threadIdx.x] += t;
    __syncthreads();
  }
  if (i < V) rowptr[i + 1] = sm[threadIdx.x];
  if (threadIdx.x == 1023) bsum[blockIdx.x] = sm[1023];
}

__global__ __launch_bounds__(1024) void k_scan2(int* __restrict__ bsum, int nb) {
  __shared__ int sm[1024];
  int v = (threadIdx.x < nb) ? bsum[threadIdx.x] : 0;
  sm[threadIdx.x] = v;
  __syncthreads();
  for (int off = 1; off < 1024; off <<= 1) {
    int t = (threadIdx.x >= off) ? sm[threadIdx.x - off] : 0;
    __syncthreads();
    sm[threadIdx.x] += t;
    __syncthreads();
  }
  if (threadIdx.x < nb) bsum[threadIdx.x] = sm[threadIdx.x] - v;  // exclusive
}

// scan3: rowptr[i+1]=inclusive, cursor[i]=exclusive
__global__ __launch_bounds__(1024) void k_scan3(int* __restrict__ rowptr,
                                                const int* __restrict__ bsum,
                                                int* __restrict__ cursor, int V) {
  int i = blockIdx.x * 1024 + threadIdx.x;
  if (i < V) {
    int v = rowptr[i + 1] + bsum[blockIdx.x];
    rowptr[i + 1] = v;
    if (i + 1 < V) cursor[i + 1] = v;
  }
  if (i == 0) {
    rowptr[0] = 0;
    cursor[0] = 0;
  }
}

__global__ __launch_bounds__(256) void k_place(const int* __restrict__ src,
                                               const int* __restrict__ dst, int E,
                                               int* __restrict__ cursor,
                                               int* __restrict__ csr_src) {
  int e = blockIdx.x * 256 + threadIdx.x;
  if (e < E) {
    int d = dst[e];
    int slot = atomicAdd(&cursor[d], 1);
    csr_src[slot] = src[e];
  }
}

__global__ __launch_bounds__(256) void k_place_idx(const int* __restrict__ dst, int E,
                                                   int* __restrict__ cursor,
                                                   int* __restrict__ members,
                                                   int* __restrict__ clmem) {
  int e = blockIdx.x * 256 + threadIdx.x;
  if (e < E) {
    int d = dst[e];
    int slot = atomicAdd(&cursor[d], 1);
    members[slot] = e;
    clmem[slot] = d;
  }
}

// ---------------- bucketed CSR build (large layers) ----------------
__global__ __launch_bounds__(256) void k_bhist(const int* __restrict__ dst, int E,
                                               int EPB, int NBLK, int NBUK,
                                               int* __restrict__ bhisto) {
  __shared__ int sm[1024];
  for (int b = threadIdx.x; b < NBUK; b += 256) sm[b] = 0;
  __syncthreads();
  int blk = blockIdx.x;
  int e0 = blk * EPB, e1 = min(e0 + EPB, E);
  for (int i = e0 + threadIdx.x; i < e1; i += 256) atomicAdd(&sm[dst[i] >> 9], 1);
  __syncthreads();
  for (int b = threadIdx.x; b < NBUK; b += 256) bhisto[b * NBLK + blk] = sm[b];
}

__global__ __launch_bounds__(256) void k_bplace(const int* __restrict__ payload,
                                                const int* __restrict__ dst, int E,
                                                int EPB, int NBLK, int NBUK,
                                                const int* __restrict__ bexcl,
                                                int2* __restrict__ ebuf) {
  __shared__ int cur[1024];
  int blk = blockIdx.x;
  for (int b = threadIdx.x; b < NBUK; b += 256) cur[b] = bexcl[b * NBLK + blk];
  __syncthreads();
  int e0 = blk * EPB, e1 = min(e0 + EPB, E);
  for (int i = e0 + threadIdx.x; i < e1; i += 256) {
    int d = dst[i];
    int slot = atomicAdd(&cur[d >> 9], 1);
    ebuf[slot] = make_int2(payload ? payload[i] : i, d);
  }
}

__global__ __launch_bounds__(256) void k_bcsr(const int2* __restrict__ ebuf,
                                              const int* __restrict__ bexcl, int E,
                                              int NBLK, int NBUK, int V,
                                              int* __restrict__ rowptr,
                                              int* __restrict__ outp) {
  __shared__ int sm[512];
  __shared__ int cur[512];
  int b = blockIdx.x;
  int t = threadIdx.x;
  int ebase = bexcl[b * NBLK];
  int eend = (b + 1 < NBUK) ? bexcl[(b + 1) * NBLK] : E;
  int dst0 = b << 9;
  sm[t] = 0;
  sm[t + 256] = 0;
  __syncthreads();
  for (int j = ebase + t; j < eend; j += 256) atomicAdd(&sm[ebuf[j].y - dst0], 1);
  __syncthreads();
  for (int off = 1; off < 512; off <<= 1) {
    int a0 = (t >= off) ? sm[t - off] : 0;
    int a1 = (t + 256 >= off) ? sm[t + 256 - off] : 0;
    __syncthreads();
    sm[t] += a0;
    sm[t + 256] += a1;
    __syncthreads();
  }
  if (b == 0 && t == 0) rowptr[0] = 0;
  int nd = V - dst0;
  if (nd > 512) nd = 512;
  for (int i = t; i < nd; i += 256) rowptr[dst0 + i + 1] = ebase + sm[i];
  cur[t] = ebase + ((t == 0) ? 0 : sm[t - 1]);
  cur[t + 256] = ebase + sm[t + 255];
  __syncthreads();
  for (int j = ebase + t; j < eend; j += 256) {
    int2 e = ebuf[j];
    int slot = atomicAdd(&cur[e.y - dst0], 1);
    outp[slot] = e.x;
  }
}

// ---------------- L1 fused conv: gather + [27][16] GEMM + bias + ReLU -------
// CIN=3 (x + px,py), COUT=16, EPG=8. Wave per node; W staged per block.
__global__ __launch_bounds__(256) void k_conv1(const int* __restrict__ rowptr,
                                               const int* __restrict__ csr_src,
                                               const float* __restrict__ x,
                                               const float* __restrict__ pos,
                                               const float* __restrict__ Wk,
                                               const float* __restrict__ R,
                                               const float* __restrict__ bias,
                                               float* __restrict__ out, int V,
                                               float inv2m) {
  constexpr int NZ = 24, NROW = 27;
  __shared__ float WL[NROW * 16];
  __shared__ float BL[16];
  __shared__ float zrow[4][32];
  int tid = threadIdx.x;
  for (int i = tid; i < NROW * 16; i += 256)
    WL[i] = (i < NZ * 16) ? Wk[i] : R[i - NZ * 16];
  if (tid < 16) BL[tid] = bias[tid];
  __syncthreads();
  int lane = tid & 63;
  int wv = tid >> 6;
  int u = lane & 7;
  int n = blockIdx.x * 4 + wv;
  if (n >= V) return;
  int start = rowptr[n], end = rowptr[n + 1];
  float z0 = 0.f, z1 = 0.f, z2 = 0.f;
  float dx = pos[3 * n], dy = pos[3 * n + 1], dz = pos[3 * n + 2];
  for (int j0 = start; j0 < end; j0 += 8) {
    int j = j0 + (lane >> 3);
    bool valid = (j < end);
    int js = valid ? j : (end - 1);
    int s = csr_src[js];
    float sx = pos[3 * s], sy = pos[3 * s + 1], sz = pos[3 * s + 2];
    float p0 = fclamp01((dx - sx) * inv2m + 0.5f);
    float p1 = fclamp01((dy - sy) * inv2m + 0.5f);
    float p2 = fclamp01((dz - sz) * inv2m + 0.5f);
    float q0 = 1.f - p0, q1 = 1.f - p1, q2 = 1.f - p2;
    float vm = valid ? 1.f : 0.f;
    float xs = x[s];
#pragma unroll
    for (int i = 0; i < 3; i++) {
      int idx = u + 8 * i;
      int ss = idx / 3;
      int k = idx - ss * 3;
      float b = ((ss & 1) ? p0 : q0) * ((ss & 2) ? p1 : q1) * ((ss & 4) ? p2 : q2) *
                vm;
      float xv = (k == 0) ? xs : ((k == 1) ? sx : sy);
      float zi = b * xv;
      if (i == 0) z0 += zi;
      else if (i == 1) z1 += zi;
      else z2 += zi;
    }
  }
#pragma unroll
  for (int m = 8; m < 64; m <<= 1) {
    z0 += __shfl_xor(z0, m);
    z1 += __shfl_xor(z1, m);
    z2 += __shfl_xor(z2, m);
  }
  float inv = 1.f / fmaxf((float)(end - start), 1.f);
  if (lane < 8) {
    zrow[wv][u] = z0 * inv;
    zrow[wv][u + 8] = z1 * inv;
    zrow[wv][u + 16] = z2 * inv;
  }
  if (lane == 8) {
    zrow[wv][24] = x[n];
    zrow[wv][25] = dx;
    zrow[wv][26] = dy;
  }
  // wave-local LDS: DS ops from one wave execute in order; no barrier needed.
  if (lane < 16) {
    float acc = BL[lane];
#pragma unroll
    for (int j = 0; j < NROW; j++) acc += zrow[wv][j] * WL[j * 16 + lane];
    out[(size_t)n * 16 + lane] = fmaxf(acc, 0.f);
  }
}

// ---------------- gather: EPG edges in parallel per wave ----------------
template <int CIN, int EPG>
__global__ __launch_bounds__(256) void k_gather(const int* __restrict__ rowptr,
                                                const int* __restrict__ csr_src,
                                                const float* __restrict__ hin,
                                                const float* __restrict__ pos,
                                                float* __restrict__ Z, int nodeBase,
                                                int nodeEnd, float inv2m) {
  constexpr int CH = CIN - 2;
  constexpr int NZ = 8 * CIN;
  constexpr int ROW = 9 * CIN;
  constexpr int LPE = 64 / EPG;
  constexpr int NE = (NZ + LPE - 1) / LPE;
  int lane = threadIdx.x & 63;
  int u = lane & (LPE - 1);
  int g = lane / LPE;
  int n = nodeBase + blockIdx.x * 4 + (threadIdx.x >> 6);
  if (n >= nodeEnd) return;
  int start = rowptr[n], end = rowptr[n + 1];
  float z[NE];
#pragma unroll
  for (int i = 0; i < NE; i++) z[i] = 0.f;
  float dx = pos[3 * n], dy = pos[3 * n + 1], dz = pos[3 * n + 2];
  for (int j0 = start; j0 < end; j0 += EPG) {
    int j = j0 + g;
    bool valid = (j < end);
    int js = valid ? j : (end - 1);
    int s = csr_src[js];
    float sx = pos[3 * s], sy = pos[3 * s + 1], sz = pos[3 * s + 2];
    float p0 = fclamp01((dx - sx) * inv2m + 0.5f);
    float p1 = fclamp01((dy - sy) * inv2m + 0.5f);
    float p2 = fclamp01((dz - sz) * inv2m + 0.5f);
    float q0 = 1.f - p0, q1 = 1.f - p1, q2 = 1.f - p2;
    float vm = valid ? 1.f : 0.f;
#pragma unroll
    for (int i = 0; i < NE; i++) {
      int idx = u + LPE * i;
      if (idx < NZ) {
        int ss = idx / CIN;
        int k = idx - ss * CIN;
        float b = ((ss & 1) ? p0 : q0) * ((ss & 2) ? p1 : q1) *
                  ((ss & 4) ? p2 : q2) * vm;
        float xv = (k < CH) ? hin[(size_t)s * CH + k] : ((k == CH) ? sx : sy);
        z[i] += b * xv;
      }
    }
  }
  if (EPG > 1) {
#pragma unroll
    for (int m = LPE; m < 64; m <<= 1) {
#pragma unroll
      for (int i = 0; i < NE; i++) z[i] += __shfl_xor(z[i], m);
    }
  }
  float inv = 1.f / fmaxf((float)(end - start), 1.f);
  float* zr = &Z[(size_t)(n - nodeBase) * ROW];
  if (lane < LPE) {
#pragma unroll
    for (int i = 0; i < NE; i++) {
      int idx = u + LPE * i;
      if (idx < NZ) zr[idx] = z[i] * inv;
    }
  }
  for (int k = lane; k < CIN; k += 64) {
    zr[NZ + k] = (k < CH) ? hin[(size_t)n * CH + k] : ((k == CH) ? dx : dy);
  }
}

// ---------------- tiled GEMM + bias + relu (large V) ----------------
template <int CIN, int COUT>
__global__ __launch_bounds__(256) void k_gemm(const float* __restrict__ Z,
                                              const float* __restrict__ Wk,
                                              const float* __restrict__ R,
                                              const float* __restrict__ bias,
                                              float* __restrict__ out, int nodeBase,
                                              int nodeCount) {
  constexpr int NZ = 8 * CIN, K = 9 * CIN;
  constexpr int NI = COUT / 16;
  constexpr int KT = 32;
  __shared__ float ZL[32][KT + 1];
  __shared__ float WL[KT][COUT];
  int tid = threadIdx.x;
  int cj = tid & 15, ng = tid >> 4;  // ng 0..15
  int tile0 = blockIdx.x * 32;
  float acc[2][NI];
#pragma unroll
  for (int a = 0; a < 2; a++)
#pragma unroll
    for (int i = 0; i < NI; i++) acc[a][i] = 0.f;
  for (int kt = 0; kt < K; kt += KT) {
#pragma unroll
    for (int l = 0; l < 4; l++) {
      int idx = tid + l * 256;
      int r = idx >> 5, c = idx & 31;
      int node = tile0 + r, k = kt + c;
      ZL[r][c] = (node < nodeCount && k < K) ? Z[(size_t)node * K + k] : 0.f;
    }
    for (int idx = tid; idx < KT * COUT; idx += 256) {
      int r = idx / COUT, c = idx - r * COUT;
      int k = kt + r;
      float w = 0.f;
      if (k < NZ)
        w = Wk[(size_t)k * COUT + c];
      else if (k < K)
        w = R[(size_t)(k - NZ) * COUT + c];
      WL[r][c] = w;
    }
    __syncthreads();
#pragma unroll
    for (int k = 0; k < KT; k++) {
      float z0 = ZL[ng][k], z1 = ZL[ng + 16][k];
#pragma unroll
      for (int i = 0; i < NI; i++) {
        float w = WL[k][cj + 16 * i];
        acc[0][i] += z0 * w;
        acc[1][i] += z1 * w;
      }
    }
    __syncthreads();
  }
#pragma unroll
  for (int a = 0; a < 2; a++) {
    int node = tile0 + ng + 16 * a;
    if (node < nodeCount) {
#pragma unroll
      for (int i = 0; i < NI; i++) {
        int c = cj + 16 * i;
        out[(size_t)(nodeBase + node) * COUT + c] = fmaxf(acc[a][i] + bias[c], 0.f);
      }
    }
  }
}

// ---------------- skinny GEMM (small V, big K): thread = (node, cout) -------
template <int CIN, int COUT>
__global__ __launch_bounds__(256) void k_gemm_skinny(
    const float* __restrict__ Z, const float* __restrict__ Wk,
    const float* __restrict__ R, const float* __restrict__ bias,
    float* __restrict__ out, int nodeCount) {
  constexpr int NZ = 8 * CIN, K = 9 * CIN;
  constexpr int NPB = 256 / COUT;  // nodes per block
  constexpr int KC = 64;
  __shared__ float ZL[NPB][KC];
  int c = threadIdx.x & (COUT - 1);
  int ln = threadIdx.x / COUT;
  int n0 = blockIdx.x * NPB;
  float acc = 0.f;
  for (int k0 = 0; k0 < K; k0 += KC) {
    __syncthreads();
    for (int i = threadIdx.x; i < NPB * KC; i += 256) {
      int nn = i / KC, kk = i - (i / KC) * KC;
      int gk = k0 + kk;
      ZL[nn][kk] =
          (n0 + nn < nodeCount && gk < K) ? Z[(size_t)(n0 + nn) * K + gk] : 0.f;
    }
    __syncthreads();
    int kmax = (K - k0 < KC) ? (K - k0) : KC;
#pragma unroll 8
    for (int kk = 0; kk < kmax; kk++) {
      int gk = k0 + kk;
      float w = (gk < NZ) ? Wk[(size_t)gk * COUT + c]
                          : R[(size_t)(gk - NZ) * COUT + c];
      acc += ZL[ln][kk] * w;
    }
  }
  int n = n0 + ln;
  if (n < nodeCount) out[(size_t)n * COUT + c] = fmaxf(acc + bias[c], 0.f);
}

// ---------------- voxel pooling ----------------
__global__ __launch_bounds__(256) void k_cluster(const float* __restrict__ pos,
                                                 const int* __restrict__ batch,
                                                 int prevCells, int Vin, int nx,
                                                 int ny, int nt,
                                                 int* __restrict__ cluster) {
  int n = blockIdx.x * 256 + threadIdx.x;
  if (n >= Vin) return;
  float px = pos[3 * n], py = pos[3 * n + 1], pz = pos[3 * n + 2];
  int b = batch ? batch[n] : (n / prevCells);
  int ix = (int)floorf(px * nx);
  ix = ix < 0 ? 0 : (ix > nx - 1 ? nx - 1 : ix);
  int iy = (int)floorf(py * ny);
  iy = iy < 0 ? 0 : (iy > ny - 1 ? ny - 1 : iy);
  int it = (int)floorf(pz * nt);
  it = it < 0 ? 0 : (it > nt - 1 ? nt - 1 : it);
  cluster[n] = ((b * nx + ix) * ny + iy) * nt + it;
}

__global__ __launch_bounds__(256) void k_cluster_count(
    const float* __restrict__ pos, const int* __restrict__ batch, int prevCells,
    int Vin, int nx, int ny, int nt, int* __restrict__ cluster,
    int* __restrict__ cnt) {
  int n = blockIdx.x * 256 + threadIdx.x;
  if (n >= Vin) return;
  float px = pos[3 * n], py = pos[3 * n + 1], pz = pos[3 * n + 2];
  int b = batch ? batch[n] : (n / prevCells);
  int ix = (int)floorf(px * nx);
  ix = ix < 0 ? 0 : (ix > nx - 1 ? nx - 1 : ix);
  int iy = (int)floorf(py * ny);
  iy = iy < 0 ? 0 : (iy > ny - 1 ? ny - 1 : iy);
  int it = (int)floorf(pz * nt);
  it = it < 0 ? 0 : (it > nt - 1 ? nt - 1 : it);
  int cl = ((b * nx + ix) * ny + iy) * nt + it;
  cluster[n] = cl;
  atomicAdd(&cnt[cl], 1);
}

// pool1 only (balanced): thread = (cluster, channel), serial member loop.
template <int C, bool MAXP>
__global__ __launch_bounds__(256) void k_pool_gather(
    const int* __restrict__ rowptr, const int* __restrict__ members,
    const float* __restrict__ h, const float* __restrict__ pos,
    float* __restrict__ featOut, float* __restrict__ posOut, int Vout) {
  int idx = blockIdx.x * 256 + threadIdx.x;
  int cl = idx / C, ch = idx - (idx / C) * C;
  if (cl >= Vout) return;
  int start = rowptr[cl], end = rowptr[cl + 1];
  float acc = 0.f, ps = 0.f;
  for (int j = start; j < end; j++) {
    int m = members[j];
    float v = h[(size_t)m * C + ch];
    acc = MAXP ? fmaxf(acc, v) : (acc + v);
    if (ch < 3) ps += pos[3 * m + ch];
  }
  float invc = 1.f / fmaxf((float)(end - start), 1.f);
  featOut[(size_t)cl * C + ch] = MAXP ? acc : acc * invc;
  if (ch < 3) posOut[3 * cl + ch] = ps * invc;
}

// pools 2-4 (skewed): member-parallel strips, segmented boundary-flush atomics.
template <int C, bool MAXP>
__global__ __launch_bounds__(256) void k_pool_strip(
    const int* __restrict__ members, const int* __restrict__ clmem,
    const float* __restrict__ h, const float* __restrict__ pos,
    float* __restrict__ feat, float* __restrict__ psum, int Vin) {
  constexpr int CPB = (C < 64) ? C : 64;
  constexpr int MPW = 64 / CPB;
  constexpr int STRIP = 16;
  int lane = threadIdx.x & 63;
  int wave = (blockIdx.x * 256 + threadIdx.x) >> 6;
  int grp = lane / CPB;
  int chp = lane - grp * CPB;
  int ch = chp + CPB * blockIdx.y;
  int base = wave * (STRIP * MPW) + grp * STRIP;
  bool doPos = (blockIdx.y == 0) && (chp < 3);
  float acc = 0.f, pacc = 0.f;
  int cur = -1;
#pragma unroll
  for (int k = 0; k < STRIP; k++) {
    int j = base + k;
    if (j < Vin) {
      int cl = clmem[j];
      int m = members[j];
      float v = h[(size_t)m * C + ch];
      float pv = doPos ? pos[3 * m + chp] : 0.f;
      if (cl != cur) {
        if (cur >= 0) {
          if (MAXP)
            atomicMax((unsigned int*)&feat[(size_t)cur * C + ch],
                      __float_as_uint(acc));
          else
            atomicAdd(&feat[(size_t)cur * C + ch], acc);
          if (doPos) atomicAdd(&psum[3 * cur + chp], pacc);
        }
        acc = v;
        pacc = pv;
        cur = cl;
      } else {
        acc = MAXP ? fmaxf(acc, v) : acc + v;
        pacc += pv;
      }
    }
  }
  if (cur >= 0) {
    if (MAXP)
      atomicMax((unsigned int*)&feat[(size_t)cur * C + ch], __float_as_uint(acc));
    else
      atomicAdd(&feat[(size_t)cur * C + ch], acc);
    if (doPos) atomicAdd(&psum[3 * cur + chp], pacc);
  }
}

template <int C, bool MEANP>
__global__ __launch_bounds__(256) void k_pool_fin(const int* __restrict__ rowptr,
                                                  const float* __restrict__ psum,
                                                  float* __restrict__ feat,
                                                  float* __restrict__ posOut,
                                                  int Vout) {
  int v = blockIdx.x * 256 + threadIdx.x;
  if (v >= Vout) return;
  float invc = 1.f / fmaxf((float)(rowptr[v + 1] - rowptr[v]), 1.f);
  posOut[3 * v] = psum[3 * v] * invc;
  posOut[3 * v + 1] = psum[3 * v + 1] * invc;
  posOut[3 * v + 2] = psum[3 * v + 2] * invc;
  if (MEANP) {
    for (int i = 0; i < C; i++) feat[(size_t)v * C + i] *= invc;
  }
}

extern "C" void kernel_launch(void* const* d_in, const int* in_sizes, int n_in,
                              void* d_out, int out_size, void* d_ws, size_t ws_size,
                              hipStream_t stream) {
  (void)in_sizes; (void)n_in; (void)out_size; (void)ws_size;
  const float* x = (const float*)d_in[0];
  const float* pos0 = (const float*)d_in[1];
  const int* batch = (const int*)d_in[2];
  const int* e0 = (const int*)d_in[3];
  const int* e1 = (const int*)d_in[4];
  const int* e2 = (const int*)d_in[5];
  const int* e3 = (const int*)d_in[6];
  const int* e4 = (const int*)d_in[7];
  const float* W1 = (const float*)d_in[8];
  const float* R1 = (const float*)d_in[9];
  const float* b1 = (const float*)d_in[10];
  const float* W2 = (const float*)d_in[11];
  const float* R2 = (const float*)d_in[12];
  const float* b2 = (const float*)d_in[13];
  const float* W3 = (const float*)d_in[14];
  const float* R3 = (const float*)d_in[15];
  const float* b3 = (const float*)d_in[16];
  const float* W4 = (const float*)d_in[17];
  const float* R4 = (const float*)d_in[18];
  const float* b4 = (const float*)d_in[19];
  const float* W5 = (const float*)d_in[20];
  const float* R5 = (const float*)d_in[21];
  const float* b5 = (const float*)d_in[22];

  float* out3 = (float*)d_out;            // 1536*128
  float* out5 = (float*)d_out + 196608;   // 192*128

  char* w = (char*)d_ws;
  auto carve = [&](size_t bytes) {
    char* p = w;
    w += (bytes + 255) & ~(size_t)255;
    return p;
  };
  int* cnt = (int*)carve(300001ull * 4);     // also bhisto [bucket][block]
  int* rowptr = (int*)carve(300001ull * 4);  // also scan tmp
  int* cursor = (int*)carve(300001ull * 4);  // also bexcl
  int* bsum = (int*)carve(1024 * 4);
  int* csr = (int*)carve(3600000ull * 4);
  int* cluster = (int*)carve(300000ull * 4);
  int* members = (int*)carve(300000ull * 4);
  int* clmem = (int*)carve(300000ull * 4);
  float* psum = (float*)carve(98304ull * 3 * 4);
  float* Zbuf = (float*)carve(8100000ull * 4);   // L2/L3 Z; also ebuf
  float* hA = (float*)carve(6291456ull * 4);     // conv outputs (max 98304*64)
  float* hB = (float*)carve(1572864ull * 4);     // pooled feats (max 98304*16)
  float* posA = (float*)carve(294912ull * 4);    // 98304*3
  float* posB = (float*)carve(36864ull * 4);     // 12288*3
  int2* ebuf = (int2*)Zbuf;                      // 3.6M*8B <= 32.4MB

  auto scan_rowptr = [&](int V) {  // cursor <- exclusive scan of cnt
    int nb = (V + 1023) / 1024;
    k_scan1<<<nb, 1024, 0, stream>>>(cnt, V, rowptr, bsum);
    k_scan2<<<1, 1024, 0, stream>>>(bsum, nb);
    k_scan3<<<nb, 1024, 0, stream>>>(rowptr, bsum, cursor, V);
  };

  auto csr_build = [&](const int* e, int E, int V) {
    hipMemsetAsync(cnt, 0, (size_t)V * 4, stream);
    k_count<<<(E + 255) / 256, 256, 0, stream>>>(e + E, E, cnt);
    scan_rowptr(V);
    k_place<<<(E + 255) / 256, 256, 0, stream>>>(e, e + E, E, cursor, csr);
  };

  auto csr_build_bucketed = [&](const int* payload, const int* dstArr, int E, int V,
                                int* outp) {
    int NBUK = (V + 511) >> 9;
    int EPB = 16384;
    int NBLK = (E + EPB - 1) / EPB;
    k_bhist<<<NBLK, 256, 0, stream>>>(dstArr, E, EPB, NBLK, NBUK, cnt);
    scan_rowptr(NBUK * NBLK);
    k_bplace<<<NBLK, 256, 0, stream>>>(payload, dstArr, E, EPB, NBLK, NBUK, cursor,
                                       ebuf);
    k_bcsr<<<NBUK, 256, 0, stream>>>(ebuf, cursor, E, NBLK, NBUK, V, rowptr, outp);
  };

  auto pool_csr = [&](const float* posIn, const int* batchIn, int prevCells, int Vin,
                      int nx, int ny, int nt) {
    int Vc = 4 * nx * ny * nt;  // B=4
    hipMemsetAsync(cnt, 0, (size_t)Vc * 4, stream);
    k_cluster_count<<<(Vin + 255) / 256, 256, 0, stream>>>(
        posIn, batchIn, prevCells, Vin, nx, ny, nt, cluster, cnt);
    scan_rowptr(Vc);
    k_place_idx<<<(Vin + 255) / 256, 256, 0, stream>>>(cluster, Vin, cursor, members,
                                                       clmem);
  };

  // ---------- Layer 1: V=300000, E=3600000, CIN=3, COUT=16 (fused) ----------
  csr_build_bucketed(e0, e0 + 3600000, 3600000, 300000, csr);
  k_conv1<<<(300000 + 3) / 4, 256, 0, stream>>>(rowptr, csr, x, pos0, W1, R1, b1, hA,
                                                300000, 20.0f);
  // pool1 (max) -> 98304, grid (64,48,8): bucketed members + balanced gather
  k_cluster<<<(300000 + 255) / 256, 256, 0, stream>>>(pos0, batch, 0, 300000, 64, 48,
                                                      8, cluster);
  csr_build_bucketed(nullptr, cluster, 300000, 98304, members);
  k_pool_gather<16, true><<<(98304 * 16 + 255) / 256, 256, 0, stream>>>(
      rowptr, members, hA, pos0, hB, posA, 98304);

  // ---------- Layer 2: V=98304, E=786432, CIN=18, COUT=64 (2 chunks) ----------
  csr_build_bucketed(e1, e1 + 786432, 786432, 98304, csr);
  for (int c = 0; c < 2; c++) {
    int base = c * 49152, n = 49152;
    k_gather<18, 2><<<(n + 3) / 4, 256, 0, stream>>>(rowptr, csr, hB, posA, Zbuf,
                                                     base, base + n, 10.0f);
    k_gemm<18, 64><<<(n + 31) / 32, 256, 0, stream>>>(Zbuf, W2, R2, b2, hA, base, n);
  }
  // pool2 (max) -> 12288: strip (skewed: empty-voxel pos=0 hot cluster)
  pool_csr(posA, nullptr, 24576, 98304, 32, 24, 4);
  hipMemsetAsync(hB, 0, 12288ull * 64 * 4, stream);
  hipMemsetAsync(psum, 0, 12288ull * 3 * 4, stream);
  k_pool_strip<64, true><<<dim3(1536, 1), 256, 0, stream>>>(members, clmem, hA, posA,
                                                            hB, psum, 98304);
  k_pool_fin<64, false><<<(12288 + 255) / 256, 256, 0, stream>>>(rowptr, psum, hB,
                                                                 posB, 12288);

  // ---------- Layer 3: V=12288, E=196608, CIN=66, COUT=128 ----------
  csr_build(e2, 196608, 12288);
  k_gather<66, 2><<<(12288 + 3) / 4, 256, 0, stream>>>(rowptr, csr, hB, posB, Zbuf,
                                                       0, 12288, 6.0f);
  k_gemm<66, 128><<<(12288 + 31) / 32, 256, 0, stream>>>(Zbuf, W3, R3, b3, hA, 0,
                                                         12288);
  // pool3 (max) -> 1536: strip
  pool_csr(posB, nullptr, 3072, 12288, 16, 12, 2);
  hipMemsetAsync(hB, 0, 1536ull * 128 * 4, stream);
  hipMemsetAsync(psum, 0, 1536ull * 3 * 4, stream);
  k_pool_strip<128, true><<<dim3(192, 2), 256, 0, stream>>>(members, clmem, hA, posB,
                                                            hB, psum, 12288);
  k_pool_fin<128, false><<<(1536 + 255) / 256, 256, 0, stream>>>(rowptr, psum, hB,
                                                                 posA, 1536);

  // ---------- Layer 4: V=1536, E=24576, CIN=130, COUT=128 -> out3 ----------
  csr_build(e3, 24576, 1536);
  k_gather<130, 1><<<(1536 + 3) / 4, 256, 0, stream>>>(rowptr, csr, hB, posA, Zbuf,
                                                       0, 1536, 3.0f);
  k_gemm_skinny<130, 128><<<768, 256, 0, stream>>>(Zbuf, W4, R4, b4, out3, 1536);
  // pool4 (mean) -> 192: strip
  pool_csr(posA, nullptr, 384, 1536, 8, 6, 1);
  hipMemsetAsync(hB, 0, 192ull * 128 * 4, stream);
  hipMemsetAsync(psum, 0, 192ull * 3 * 4, stream);
  k_pool_strip<128, false><<<dim3(24, 2), 256, 0, stream>>>(members, clmem, out3,
                                                            posA, hB, psum, 1536);
  k_pool_fin<128, true><<<1, 256, 0, stream>>>(rowptr, psum, hB, posB, 192);

  // ---------- Layer 5: V=192, E=3072, CIN=130, COUT=128 -> out5 ----------
  csr_build(e4, 3072, 192);
  k_gather<130, 1><<<(192 + 3) / 4, 256, 0, stream>>>(rowptr, csr, hB, posB, Zbuf, 0,
                                                      192, 1.5f);
  k_gemm_skinny<130, 128><<<96, 256, 0, stream>>>(Zbuf, W5, R5, b5, out5, 192);
}

// Round 9
// 1294.046 us; speedup vs baseline: 1.1245x; 1.1245x over previous
//
#include <hip/hip_runtime.h>
#include <stdint.h>

// EVGNN backbone on MI355X.
// L1: fused conv (gather EPG=8 + butterfly + per-wave LDS Z + [27][16] GEMM).
// L2/L3 (R8): k_gemm_mid — thread=(cout,row), NB nodes/block, Z chunk in LDS,
// W read from L2 per (k,c), 4 node-accumulators per thread. Replaces the
// 384-block barrier-locked tiled GEMM (200us @ 15% VALU, 17% occ).
// L4/L5: skinny GEMM. CSR build: bucketed counting sort (write-amp ~1).
// Pooling: pool1 balanced gather; pools 2-4 strip kernel (skew-proof).

__device__ __forceinline__ float fclamp01(float v) { return fminf(fmaxf(v, 0.f), 1.f); }

// ---------------- simple CSR build (small layers) ----------------
__global__ __launch_bounds__(256) void k_count(const int* __restrict__ dst, int E,
                                               int* __restrict__ cnt) {
  int e = blockIdx.x * 256 + threadIdx.x;
  if (e < E) atomicAdd(&cnt[dst[e]], 1);
}

__global__ __launch_bounds__(1024) void k_scan1(const int* __restrict__ cnt, int V,
                                                int* __restrict__ rowptr,
                                                int* __restrict__ bsum) {
  __shared__ int sm[1024];
  int i = blockIdx.x * 1024 + threadIdx.x;
  int v = (i < V) ? cnt[i] : 0;
  sm[threadIdx.x] = v;
  __syncthreads();
  for (int off = 1; off < 1024; off <<= 1) {
    int t = (threadIdx.x >= off) ? sm[threadIdx.x - off] : 0;
    __syncthreads();
    sm[threadIdx.x] += t;
    __syncthreads();
  }
  if (i < V) rowptr[i + 1] = sm[threadIdx.x];
  if (threadIdx.x == 1023) bsum[blockIdx.x] = sm[1023];
}

__global__ __launch_bounds__(1024) void k_scan2(int* __restrict__ bsum, int nb) {
  __shared__ int sm[1024];
  int v = (threadIdx.x < nb) ? bsum[threadIdx.x] : 0;
  sm[threadIdx.x] = v;
  __syncthreads();
  for (int off = 1; off < 1024; off <<= 1) {
    int t = (threadIdx.x >= off) ? sm[threadIdx.x - off] : 0;
    __syncthreads();
    sm[threadIdx.x] += t;
    __syncthreads();
  }
  if (threadIdx.x < nb) bsum[threadIdx.x] = sm[threadIdx.x] - v;  // exclusive
}

// scan3: rowptr[i+1]=inclusive, cursor[i]=exclusive
__global__ __launch_bounds__(1024) void k_scan3(int* __restrict__ rowptr,
                                                const int* __restrict__ bsum,
                                                int* __restrict__ cursor, int V) {
  int i = blockIdx.x * 1024 + threadIdx.x;
  if (i < V) {
    int v = rowptr[i + 1] + bsum[blockIdx.x];
    rowptr[i + 1] = v;
    if (i + 1 < V) cursor[i + 1] = v;
  }
  if (i == 0) {
    rowptr[0] = 0;
    cursor[0] = 0;
  }
}

__global__ __launch_bounds__(256) void k_place(const int* __restrict__ src,
                                               const int* __restrict__ dst, int E,
                                               int* __restrict__ cursor,
                                               int* __restrict__ csr_src) {
  int e = blockIdx.x * 256 + threadIdx.x;
  if (e < E) {
    int d = dst[e];
    int slot = atomicAdd(&cursor[d], 1);
    csr_src[slot] = src[e];
  }
}

__global__ __launch_bounds__(256) void k_place_idx(const int* __restrict__ dst, int E,
                                                   int* __restrict__ cursor,
                                                   int* __restrict__ members,
                                                   int* __restrict__ clmem) {
  int e = blockIdx.x * 256 + threadIdx.x;
  if (e < E) {
    int d = dst[e];
    int slot = atomicAdd(&cursor[d], 1);
    members[slot] = e;
    clmem[slot] = d;
  }
}

// ---------------- bucketed CSR build (large layers) ----------------
__global__ __launch_bounds__(256) void k_bhist(const int* __restrict__ dst, int E,
                                               int EPB, int NBLK, int NBUK,
                                               int* __restrict__ bhisto) {
  __shared__ int sm[1024];
  for (int b = threadIdx.x; b < NBUK; b += 256) sm[b] = 0;
  __syncthreads();
  int blk = blockIdx.x;
  int e0 = blk * EPB, e1 = min(e0 + EPB, E);
  for (int i = e0 + threadIdx.x; i < e1; i += 256) atomicAdd(&sm[dst[i] >> 9], 1);
  __syncthreads();
  for (int b = threadIdx.x; b < NBUK; b += 256) bhisto[b * NBLK + blk] = sm[b];
}

__global__ __launch_bounds__(256) void k_bplace(const int* __restrict__ payload,
                                                const int* __restrict__ dst, int E,
                                                int EPB, int NBLK, int NBUK,
                                                const int* __restrict__ bexcl,
                                                int2* __restrict__ ebuf) {
  __shared__ int cur[1024];
  int blk = blockIdx.x;
  for (int b = threadIdx.x; b < NBUK; b += 256) cur[b] = bexcl[b * NBLK + blk];
  __syncthreads();
  int e0 = blk * EPB, e1 = min(e0 + EPB, E);
  for (int i = e0 + threadIdx.x; i < e1; i += 256) {
    int d = dst[i];
    int slot = atomicAdd(&cur[d >> 9], 1);
    ebuf[slot] = make_int2(payload ? payload[i] : i, d);
  }
}

__global__ __launch_bounds__(256) void k_bcsr(const int2* __restrict__ ebuf,
                                              const int* __restrict__ bexcl, int E,
                                              int NBLK, int NBUK, int V,
                                              int* __restrict__ rowptr,
                                              int* __restrict__ outp) {
  __shared__ int sm[512];
  __shared__ int cur[512];
  int b = blockIdx.x;
  int t = threadIdx.x;
  int ebase = bexcl[b * NBLK];
  int eend = (b + 1 < NBUK) ? bexcl[(b + 1) * NBLK] : E;
  int dst0 = b << 9;
  sm[t] = 0;
  sm[t + 256] = 0;
  __syncthreads();
  for (int j = ebase + t; j < eend; j += 256) atomicAdd(&sm[ebuf[j].y - dst0], 1);
  __syncthreads();
  for (int off = 1; off < 512; off <<= 1) {
    int a0 = (t >= off) ? sm[t - off] : 0;
    int a1 = (t + 256 >= off) ? sm[t + 256 - off] : 0;
    __syncthreads();
    sm[t] += a0;
    sm[t + 256] += a1;
    __syncthreads();
  }
  if (b == 0 && t == 0) rowptr[0] = 0;
  int nd = V - dst0;
  if (nd > 512) nd = 512;
  for (int i = t; i < nd; i += 256) rowptr[dst0 + i + 1] = ebase + sm[i];
  cur[t] = ebase + ((t == 0) ? 0 : sm[t - 1]);
  cur[t + 256] = ebase + sm[t + 255];
  __syncthreads();
  for (int j = ebase + t; j < eend; j += 256) {
    int2 e = ebuf[j];
    int slot = atomicAdd(&cur[e.y - dst0], 1);
    outp[slot] = e.x;
  }
}

// ---------------- L1 fused conv: gather + [27][16] GEMM + bias + ReLU -------
__global__ __launch_bounds__(256) void k_conv1(const int* __restrict__ rowptr,
                                               const int* __restrict__ csr_src,
                                               const float* __restrict__ x,
                                               const float* __restrict__ pos,
                                               const float* __restrict__ Wk,
                                               const float* __restrict__ R,
                                               const float* __restrict__ bias,
                                               float* __restrict__ out, int V,
                                               float inv2m) {
  constexpr int NZ = 24, NROW = 27;
  __shared__ float WL[NROW * 16];
  __shared__ float BL[16];
  __shared__ float zrow[4][32];
  int tid = threadIdx.x;
  for (int i = tid; i < NROW * 16; i += 256)
    WL[i] = (i < NZ * 16) ? Wk[i] : R[i - NZ * 16];
  if (tid < 16) BL[tid] = bias[tid];
  __syncthreads();
  int lane = tid & 63;
  int wv = tid >> 6;
  int u = lane & 7;
  int n = blockIdx.x * 4 + wv;
  if (n >= V) return;
  int start = rowptr[n], end = rowptr[n + 1];
  float z0 = 0.f, z1 = 0.f, z2 = 0.f;
  float dx = pos[3 * n], dy = pos[3 * n + 1], dz = pos[3 * n + 2];
  for (int j0 = start; j0 < end; j0 += 8) {
    int j = j0 + (lane >> 3);
    bool valid = (j < end);
    int js = valid ? j : (end - 1);
    int s = csr_src[js];
    float sx = pos[3 * s], sy = pos[3 * s + 1], sz = pos[3 * s + 2];
    float p0 = fclamp01((dx - sx) * inv2m + 0.5f);
    float p1 = fclamp01((dy - sy) * inv2m + 0.5f);
    float p2 = fclamp01((dz - sz) * inv2m + 0.5f);
    float q0 = 1.f - p0, q1 = 1.f - p1, q2 = 1.f - p2;
    float vm = valid ? 1.f : 0.f;
    float xs = x[s];
#pragma unroll
    for (int i = 0; i < 3; i++) {
      int idx = u + 8 * i;
      int ss = idx / 3;
      int k = idx - ss * 3;
      float b = ((ss & 1) ? p0 : q0) * ((ss & 2) ? p1 : q1) * ((ss & 4) ? p2 : q2) *
                vm;
      float xv = (k == 0) ? xs : ((k == 1) ? sx : sy);
      float zi = b * xv;
      if (i == 0) z0 += zi;
      else if (i == 1) z1 += zi;
      else z2 += zi;
    }
  }
#pragma unroll
  for (int m = 8; m < 64; m <<= 1) {
    z0 += __shfl_xor(z0, m);
    z1 += __shfl_xor(z1, m);
    z2 += __shfl_xor(z2, m);
  }
  float inv = 1.f / fmaxf((float)(end - start), 1.f);
  if (lane < 8) {
    zrow[wv][u] = z0 * inv;
    zrow[wv][u + 8] = z1 * inv;
    zrow[wv][u + 16] = z2 * inv;
  }
  if (lane == 8) {
    zrow[wv][24] = x[n];
    zrow[wv][25] = dx;
    zrow[wv][26] = dy;
  }
  // wave-local LDS: DS ops from one wave execute in order; no barrier needed.
  if (lane < 16) {
    float acc = BL[lane];
#pragma unroll
    for (int j = 0; j < NROW; j++) acc += zrow[wv][j] * WL[j * 16 + lane];
    out[(size_t)n * 16 + lane] = fmaxf(acc, 0.f);
  }
}

// ---------------- gather: EPG edges in parallel per wave ----------------
template <int CIN, int EPG>
__global__ __launch_bounds__(256) void k_gather(const int* __restrict__ rowptr,
                                                const int* __restrict__ csr_src,
                                                const float* __restrict__ hin,
                                                const float* __restrict__ pos,
                                                float* __restrict__ Z, int nodeBase,
                                                int nodeEnd, float inv2m) {
  constexpr int CH = CIN - 2;
  constexpr int NZ = 8 * CIN;
  constexpr int ROW = 9 * CIN;
  constexpr int LPE = 64 / EPG;
  constexpr int NE = (NZ + LPE - 1) / LPE;
  int lane = threadIdx.x & 63;
  int u = lane & (LPE - 1);
  int g = lane / LPE;
  int n = nodeBase + blockIdx.x * 4 + (threadIdx.x >> 6);
  if (n >= nodeEnd) return;
  int start = rowptr[n], end = rowptr[n + 1];
  float z[NE];
#pragma unroll
  for (int i = 0; i < NE; i++) z[i] = 0.f;
  float dx = pos[3 * n], dy = pos[3 * n + 1], dz = pos[3 * n + 2];
  for (int j0 = start; j0 < end; j0 += EPG) {
    int j = j0 + g;
    bool valid = (j < end);
    int js = valid ? j : (end - 1);
    int s = csr_src[js];
    float sx = pos[3 * s], sy = pos[3 * s + 1], sz = pos[3 * s + 2];
    float p0 = fclamp01((dx - sx) * inv2m + 0.5f);
    float p1 = fclamp01((dy - sy) * inv2m + 0.5f);
    float p2 = fclamp01((dz - sz) * inv2m + 0.5f);
    float q0 = 1.f - p0, q1 = 1.f - p1, q2 = 1.f - p2;
    float vm = valid ? 1.f : 0.f;
#pragma unroll
    for (int i = 0; i < NE; i++) {
      int idx = u + LPE * i;
      if (idx < NZ) {
        int ss = idx / CIN;
        int k = idx - ss * CIN;
        float b = ((ss & 1) ? p0 : q0) * ((ss & 2) ? p1 : q1) *
                  ((ss & 4) ? p2 : q2) * vm;
        float xv = (k < CH) ? hin[(size_t)s * CH + k] : ((k == CH) ? sx : sy);
        z[i] += b * xv;
      }
    }
  }
  if (EPG > 1) {
#pragma unroll
    for (int m = LPE; m < 64; m <<= 1) {
#pragma unroll
      for (int i = 0; i < NE; i++) z[i] += __shfl_xor(z[i], m);
    }
  }
  float inv = 1.f / fmaxf((float)(end - start), 1.f);
  float* zr = &Z[(size_t)(n - nodeBase) * ROW];
  if (lane < LPE) {
#pragma unroll
    for (int i = 0; i < NE; i++) {
      int idx = u + LPE * i;
      if (idx < NZ) zr[idx] = z[i] * inv;
    }
  }
  for (int k = lane; k < CIN; k += 64) {
    zr[NZ + k] = (k < CH) ? hin[(size_t)n * CH + k] : ((k == CH) ? dx : dy);
  }
}

// ------- mid GEMM (L2/L3): thread=(cout,row), NB nodes/block, W from L2 -----
template <int CIN, int COUT, int NB>
__global__ __launch_bounds__(256) void k_gemm_mid(
    const float* __restrict__ Z, const float* __restrict__ Wk,
    const float* __restrict__ R, const float* __restrict__ bias,
    float* __restrict__ out, int nodeBase, int nodeCount) {
  constexpr int NZ = 8 * CIN, K = 9 * CIN;
  constexpr int ROWS = 256 / COUT;  // thread-rows per block
  constexpr int NPT = NB / ROWS;    // nodes per thread
  constexpr int KC = 64;
  __shared__ float ZL[NB][KC];
  int c = threadIdx.x & (COUT - 1);
  int r = threadIdx.x / COUT;
  int n0 = blockIdx.x * NB;
  float acc[NPT];
#pragma unroll
  for (int t = 0; t < NPT; t++) acc[t] = 0.f;
  for (int k0 = 0; k0 < K; k0 += KC) {
    __syncthreads();
    for (int i = threadIdx.x; i < NB * KC; i += 256) {
      int nn = i / KC, kk = i - nn * KC;
      int gk = k0 + kk;
      ZL[nn][kk] =
          (n0 + nn < nodeCount && gk < K) ? Z[(size_t)(n0 + nn) * K + gk] : 0.f;
    }
    __syncthreads();
    int kc = (K - k0 < KC) ? (K - k0) : KC;
#pragma unroll 4
    for (int kk = 0; kk < kc; kk++) {
      int gk = k0 + kk;
      float w = (gk < NZ) ? Wk[(size_t)gk * COUT + c]
                          : R[(size_t)(gk - NZ) * COUT + c];
#pragma unroll
      for (int t = 0; t < NPT; t++) acc[t] += ZL[r * NPT + t][kk] * w;
    }
  }
#pragma unroll
  for (int t = 0; t < NPT; t++) {
    int node = n0 + r * NPT + t;
    if (node < nodeCount)
      out[(size_t)(nodeBase + node) * COUT + c] = fmaxf(acc[t] + bias[c], 0.f);
  }
}

// ---------------- skinny GEMM (small V, big K): thread = (node, cout) -------
template <int CIN, int COUT>
__global__ __launch_bounds__(256) void k_gemm_skinny(
    const float* __restrict__ Z, const float* __restrict__ Wk,
    const float* __restrict__ R, const float* __restrict__ bias,
    float* __restrict__ out, int nodeCount) {
  constexpr int NZ = 8 * CIN, K = 9 * CIN;
  constexpr int NPB = 256 / COUT;  // nodes per block
  constexpr int KC = 64;
  __shared__ float ZL[NPB][KC];
  int c = threadIdx.x & (COUT - 1);
  int ln = threadIdx.x / COUT;
  int n0 = blockIdx.x * NPB;
  float acc = 0.f;
  for (int k0 = 0; k0 < K; k0 += KC) {
    __syncthreads();
    for (int i = threadIdx.x; i < NPB * KC; i += 256) {
      int nn = i / KC, kk = i - (i / KC) * KC;
      int gk = k0 + kk;
      ZL[nn][kk] =
          (n0 + nn < nodeCount && gk < K) ? Z[(size_t)(n0 + nn) * K + gk] : 0.f;
    }
    __syncthreads();
    int kmax = (K - k0 < KC) ? (K - k0) : KC;
#pragma unroll 8
    for (int kk = 0; kk < kmax; kk++) {
      int gk = k0 + kk;
      float w = (gk < NZ) ? Wk[(size_t)gk * COUT + c]
                          : R[(size_t)(gk - NZ) * COUT + c];
      acc += ZL[ln][kk] * w;
    }
  }
  int n = n0 + ln;
  if (n < nodeCount) out[(size_t)n * COUT + c] = fmaxf(acc + bias[c], 0.f);
}

// ---------------- voxel pooling ----------------
__global__ __launch_bounds__(256) void k_cluster(const float* __restrict__ pos,
                                                 const int* __restrict__ batch,
                                                 int prevCells, int Vin, int nx,
                                                 int ny, int nt,
                                                 int* __restrict__ cluster) {
  int n = blockIdx.x * 256 + threadIdx.x;
  if (n >= Vin) return;
  float px = pos[3 * n], py = pos[3 * n + 1], pz = pos[3 * n + 2];
  int b = batch ? batch[n] : (n / prevCells);
  int ix = (int)floorf(px * nx);
  ix = ix < 0 ? 0 : (ix > nx - 1 ? nx - 1 : ix);
  int iy = (int)floorf(py * ny);
  iy = iy < 0 ? 0 : (iy > ny - 1 ? ny - 1 : iy);
  int it = (int)floorf(pz * nt);
  it = it < 0 ? 0 : (it > nt - 1 ? nt - 1 : it);
  cluster[n] = ((b * nx + ix) * ny + iy) * nt + it;
}

__global__ __launch_bounds__(256) void k_cluster_count(
    const float* __restrict__ pos, const int* __restrict__ batch, int prevCells,
    int Vin, int nx, int ny, int nt, int* __restrict__ cluster,
    int* __restrict__ cnt) {
  int n = blockIdx.x * 256 + threadIdx.x;
  if (n >= Vin) return;
  float px = pos[3 * n], py = pos[3 * n + 1], pz = pos[3 * n + 2];
  int b = batch ? batch[n] : (n / prevCells);
  int ix = (int)floorf(px * nx);
  ix = ix < 0 ? 0 : (ix > nx - 1 ? nx - 1 : ix);
  int iy = (int)floorf(py * ny);
  iy = iy < 0 ? 0 : (iy > ny - 1 ? ny - 1 : iy);
  int it = (int)floorf(pz * nt);
  it = it < 0 ? 0 : (it > nt - 1 ? nt - 1 : it);
  int cl = ((b * nx + ix) * ny + iy) * nt + it;
  cluster[n] = cl;
  atomicAdd(&cnt[cl], 1);
}

// pool1 only (balanced): thread = (cluster, channel), serial member loop.
template <int C, bool MAXP>
__global__ __launch_bounds__(256) void k_pool_gather(
    const int* __restrict__ rowptr, const int* __restrict__ members,
    const float* __restrict__ h, const float* __restrict__ pos,
    float* __restrict__ featOut, float* __restrict__ posOut, int Vout) {
  int idx = blockIdx.x * 256 + threadIdx.x;
  int cl = idx / C, ch = idx - (idx / C) * C;
  if (cl >= Vout) return;
  int start = rowptr[cl], end = rowptr[cl + 1];
  float acc = 0.f, ps = 0.f;
  for (int j = start; j < end; j++) {
    int m = members[j];
    float v = h[(size_t)m * C + ch];
    acc = MAXP ? fmaxf(acc, v) : (acc + v);
    if (ch < 3) ps += pos[3 * m + ch];
  }
  float invc = 1.f / fmaxf((float)(end - start), 1.f);
  featOut[(size_t)cl * C + ch] = MAXP ? acc : acc * invc;
  if (ch < 3) posOut[3 * cl + ch] = ps * invc;
}

// pools 2-4 (skewed): member-parallel strips, segmented boundary-flush atomics.
template <int C, bool MAXP>
__global__ __launch_bounds__(256) void k_pool_strip(
    const int* __restrict__ members, const int* __restrict__ clmem,
    const float* __restrict__ h, const float* __restrict__ pos,
    float* __restrict__ feat, float* __restrict__ psum, int Vin) {
  constexpr int CPB = (C < 64) ? C : 64;
  constexpr int MPW = 64 / CPB;
  constexpr int STRIP = 16;
  int lane = threadIdx.x & 63;
  int wave = (blockIdx.x * 256 + threadIdx.x) >> 6;
  int grp = lane / CPB;
  int chp = lane - grp * CPB;
  int ch = chp + CPB * blockIdx.y;
  int base = wave * (STRIP * MPW) + grp * STRIP;
  bool doPos = (blockIdx.y == 0) && (chp < 3);
  float acc = 0.f, pacc = 0.f;
  int cur = -1;
#pragma unroll
  for (int k = 0; k < STRIP; k++) {
    int j = base + k;
    if (j < Vin) {
      int cl = clmem[j];
      int m = members[j];
      float v = h[(size_t)m * C + ch];
      float pv = doPos ? pos[3 * m + chp] : 0.f;
      if (cl != cur) {
        if (cur >= 0) {
          if (MAXP)
            atomicMax((unsigned int*)&feat[(size_t)cur * C + ch],
                      __float_as_uint(acc));
          else
            atomicAdd(&feat[(size_t)cur * C + ch], acc);
          if (doPos) atomicAdd(&psum[3 * cur + chp], pacc);
        }
        acc = v;
        pacc = pv;
        cur = cl;
      } else {
        acc = MAXP ? fmaxf(acc, v) : acc + v;
        pacc += pv;
      }
    }
  }
  if (cur >= 0) {
    if (MAXP)
      atomicMax((unsigned int*)&feat[(size_t)cur * C + ch], __float_as_uint(acc));
    else
      atomicAdd(&feat[(size_t)cur * C + ch], acc);
    if (doPos) atomicAdd(&psum[3 * cur + chp], pacc);
  }
}

template <int C, bool MEANP>
__global__ __launch_bounds__(256) void k_pool_fin(const int* __restrict__ rowptr,
                                                  const float* __restrict__ psum,
                                                  float* __restrict__ feat,
                                                  float* __restrict__ posOut,
                                                  int Vout) {
  int v = blockIdx.x * 256 + threadIdx.x;
  if (v >= Vout) return;
  float invc = 1.f / fmaxf((float)(rowptr[v + 1] - rowptr[v]), 1.f);
  posOut[3 * v] = psum[3 * v] * invc;
  posOut[3 * v + 1] = psum[3 * v + 1] * invc;
  posOut[3 * v + 2] = psum[3 * v + 2] * invc;
  if (MEANP) {
    for (int i = 0; i < C; i++) feat[(size_t)v * C + i] *= invc;
  }
}

extern "C" void kernel_launch(void* const* d_in, const int* in_sizes, int n_in,
                              void* d_out, int out_size, void* d_ws, size_t ws_size,
                              hipStream_t stream) {
  (void)in_sizes; (void)n_in; (void)out_size; (void)ws_size;
  const float* x = (const float*)d_in[0];
  const float* pos0 = (const float*)d_in[1];
  const int* batch = (const int*)d_in[2];
  const int* e0 = (const int*)d_in[3];
  const int* e1 = (const int*)d_in[4];
  const int* e2 = (const int*)d_in[5];
  const int* e3 = (const int*)d_in[6];
  const int* e4 = (const int*)d_in[7];
  const float* W1 = (const float*)d_in[8];
  const float* R1 = (const float*)d_in[9];
  const float* b1 = (const float*)d_in[10];
  const float* W2 = (const float*)d_in[11];
  const float* R2 = (const float*)d_in[12];
  const float* b2 = (const float*)d_in[13];
  const float* W3 = (const float*)d_in[14];
  const float* R3 = (const float*)d_in[15];
  const float* b3 = (const float*)d_in[16];
  const float* W4 = (const float*)d_in[17];
  const float* R4 = (const float*)d_in[18];
  const float* b4 = (const float*)d_in[19];
  const float* W5 = (const float*)d_in[20];
  const float* R5 = (const float*)d_in[21];
  const float* b5 = (const float*)d_in[22];

  float* out3 = (float*)d_out;            // 1536*128
  float* out5 = (float*)d_out + 196608;   // 192*128

  char* w = (char*)d_ws;
  auto carve = [&](size_t bytes) {
    char* p = w;
    w += (bytes + 255) & ~(size_t)255;
    return p;
  };
  int* cnt = (int*)carve(300001ull * 4);     // also bhisto [bucket][block]
  int* rowptr = (int*)carve(300001ull * 4);  // also scan tmp
  int* cursor = (int*)carve(300001ull * 4);  // also bexcl
  int* bsum = (int*)carve(1024 * 4);
  int* csr = (int*)carve(3600000ull * 4);
  int* cluster = (int*)carve(300000ull * 4);
  int* members = (int*)carve(300000ull * 4);
  int* clmem = (int*)carve(300000ull * 4);
  float* psum = (float*)carve(98304ull * 3 * 4);
  float* Zbuf = (float*)carve(8100000ull * 4);   // L2/L3 Z; also ebuf
  float* hA = (float*)carve(6291456ull * 4);     // conv outputs (max 98304*64)
  float* hB = (float*)carve(1572864ull * 4);     // pooled feats (max 98304*16)
  float* posA = (float*)carve(294912ull * 4);    // 98304*3
  float* posB = (float*)carve(36864ull * 4);     // 12288*3
  int2* ebuf = (int2*)Zbuf;                      // 3.6M*8B <= 32.4MB

  auto scan_rowptr = [&](int V) {  // cursor <- exclusive scan of cnt
    int nb = (V + 1023) / 1024;
    k_scan1<<<nb, 1024, 0, stream>>>(cnt, V, rowptr, bsum);
    k_scan2<<<1, 1024, 0, stream>>>(bsum, nb);
    k_scan3<<<nb, 1024, 0, stream>>>(rowptr, bsum, cursor, V);
  };

  auto csr_build = [&](const int* e, int E, int V) {
    hipMemsetAsync(cnt, 0, (size_t)V * 4, stream);
    k_count<<<(E + 255) / 256, 256, 0, stream>>>(e + E, E, cnt);
    scan_rowptr(V);
    k_place<<<(E + 255) / 256, 256, 0, stream>>>(e, e + E, E, cursor, csr);
  };

  auto csr_build_bucketed = [&](const int* payload, const int* dstArr, int E, int V,
                                int* outp) {
    int NBUK = (V + 511) >> 9;
    int EPB = 16384;
    int NBLK = (E + EPB - 1) / EPB;
    k_bhist<<<NBLK, 256, 0, stream>>>(dstArr, E, EPB, NBLK, NBUK, cnt);
    scan_rowptr(NBUK * NBLK);
    k_bplace<<<NBLK, 256, 0, stream>>>(payload, dstArr, E, EPB, NBLK, NBUK, cursor,
                                       ebuf);
    k_bcsr<<<NBUK, 256, 0, stream>>>(ebuf, cursor, E, NBLK, NBUK, V, rowptr, outp);
  };

  auto pool_csr = [&](const float* posIn, const int* batchIn, int prevCells, int Vin,
                      int nx, int ny, int nt) {
    int Vc = 4 * nx * ny * nt;  // B=4
    hipMemsetAsync(cnt, 0, (size_t)Vc * 4, stream);
    k_cluster_count<<<(Vin + 255) / 256, 256, 0, stream>>>(
        posIn, batchIn, prevCells, Vin, nx, ny, nt, cluster, cnt);
    scan_rowptr(Vc);
    k_place_idx<<<(Vin + 255) / 256, 256, 0, stream>>>(cluster, Vin, cursor, members,
                                                       clmem);
  };

  // ---------- Layer 1: V=300000, E=3600000, CIN=3, COUT=16 (fused) ----------
  csr_build_bucketed(e0, e0 + 3600000, 3600000, 300000, csr);
  k_conv1<<<(300000 + 3) / 4, 256, 0, stream>>>(rowptr, csr, x, pos0, W1, R1, b1, hA,
                                                300000, 20.0f);
  // pool1 (max) -> 98304, grid (64,48,8): bucketed members + balanced gather
  k_cluster<<<(300000 + 255) / 256, 256, 0, stream>>>(pos0, batch, 0, 300000, 64, 48,
                                                      8, cluster);
  csr_build_bucketed(nullptr, cluster, 300000, 98304, members);
  k_pool_gather<16, true><<<(98304 * 16 + 255) / 256, 256, 0, stream>>>(
      rowptr, members, hA, pos0, hB, posA, 98304);

  // ---------- Layer 2: V=98304, E=786432, CIN=18, COUT=64 (2 chunks) ----------
  csr_build_bucketed(e1, e1 + 786432, 786432, 98304, csr);
  for (int c = 0; c < 2; c++) {
    int base = c * 49152, n = 49152;
    k_gather<18, 2><<<(n + 3) / 4, 256, 0, stream>>>(rowptr, csr, hB, posA, Zbuf,
                                                     base, base + n, 10.0f);
    k_gemm_mid<18, 64, 16><<<(n + 15) / 16, 256, 0, stream>>>(Zbuf, W2, R2, b2, hA,
                                                              base, n);
  }
  // pool2 (max) -> 12288: strip (skewed: empty-voxel pos=0 hot cluster)
  pool_csr(posA, nullptr, 24576, 98304, 32, 24, 4);
  hipMemsetAsync(hB, 0, 12288ull * 64 * 4, stream);
  hipMemsetAsync(psum, 0, 12288ull * 3 * 4, stream);
  k_pool_strip<64, true><<<dim3(1536, 1), 256, 0, stream>>>(members, clmem, hA, posA,
                                                            hB, psum, 98304);
  k_pool_fin<64, false><<<(12288 + 255) / 256, 256, 0, stream>>>(rowptr, psum, hB,
                                                                 posB, 12288);

  // ---------- Layer 3: V=12288, E=196608, CIN=66, COUT=128 ----------
  csr_build(e2, 196608, 12288);
  k_gather<66, 2><<<(12288 + 3) / 4, 256, 0, stream>>>(rowptr, csr, hB, posB, Zbuf,
                                                       0, 12288, 6.0f);
  k_gemm_mid<66, 128, 8><<<(12288 + 7) / 8, 256, 0, stream>>>(Zbuf, W3, R3, b3, hA,
                                                              0, 12288);
  // pool3 (max) -> 1536: strip
  pool_csr(posB, nullptr, 3072, 12288, 16, 12, 2);
  hipMemsetAsync(hB, 0, 1536ull * 128 * 4, stream);
  hipMemsetAsync(psum, 0, 1536ull * 3 * 4, stream);
  k_pool_strip<128, true><<<dim3(192, 2), 256, 0, stream>>>(members, clmem, hA, posB,
                                                            hB, psum, 12288);
  k_pool_fin<128, false><<<(1536 + 255) / 256, 256, 0, stream>>>(rowptr, psum, hB,
                                                                 posA, 1536);

  // ---------- Layer 4: V=1536, E=24576, CIN=130, COUT=128 -> out3 ----------
  csr_build(e3, 24576, 1536);
  k_gather<130, 1><<<(1536 + 3) / 4, 256, 0, stream>>>(rowptr, csr, hB, posA, Zbuf,
                                                       0, 1536, 3.0f);
  k_gemm_skinny<130, 128><<<768, 256, 0, stream>>>(Zbuf, W4, R4, b4, out3, 1536);
  // pool4 (mean) -> 192: strip
  pool_csr(posA, nullptr, 384, 1536, 8, 6, 1);
  hipMemsetAsync(hB, 0, 192ull * 128 * 4, stream);
  hipMemsetAsync(psum, 0, 192ull * 3 * 4, stream);
  k_pool_strip<128, false><<<dim3(24, 2), 256, 0, stream>>>(members, clmem, out3,
                                                            posA, hB, psum, 1536);
  k_pool_fin<128, true><<<1, 256, 0, stream>>>(rowptr, psum, hB, posB, 192);

  // ---------- Layer 5: V=192, E=3072, CIN=130, COUT=128 -> out5 ----------
  csr_build(e4, 3072, 192);
  k_gather<130, 1><<<(192 + 3) / 4, 256, 0, stream>>>(rowptr, csr, hB, posB, Zbuf, 0,
                                                      192, 1.5f);
  k_gemm_skinny<130, 128><<<96, 256, 0, stream>>>(Zbuf, W5, R5, b5, out5, 192);
}

// Round 10
// 1255.610 us; speedup vs baseline: 1.1590x; 1.0306x over previous
//
#include <hip/hip_runtime.h>
#include <stdint.h>

// EVGNN backbone on MI355X.
// L1: fused conv — pos4 (px,py,pz,x) packed loads (R9), corner-major basis
// (1 basis product + 3 FMA per lane per edge), butterfly reduce, per-wave LDS
// Z row, inline [27][16] GEMM.
// L2/L3: gather -> Z -> k_gemm_mid. L4/L5: skinny GEMM + one-block CSR (R9).
// CSR build: bucketed counting sort for large layers (write-amp ~1).
// Pooling: pool1 balanced gather; pool2 strip; pools 3/4 one-block CSR + strip.

__device__ __forceinline__ float fclamp01(float v) { return fminf(fmaxf(v, 0.f), 1.f); }

// ---------------- simple CSR build pieces ----------------
__global__ __launch_bounds__(256) void k_count(const int* __restrict__ dst, int E,
                                               int* __restrict__ cnt) {
  int e = blockIdx.x * 256 + threadIdx.x;
  if (e < E) atomicAdd(&cnt[dst[e]], 1);
}

__global__ __launch_bounds__(1024) void k_scan1(const int* __restrict__ cnt, int V,
                                                int* __restrict__ rowptr,
                                                int* __restrict__ bsum) {
  __shared__ int sm[1024];
  int i = blockIdx.x * 1024 + threadIdx.x;
  int v = (i < V) ? cnt[i] : 0;
  sm[threadIdx.x] = v;
  __syncthreads();
  for (int off = 1; off < 1024; off <<= 1) {
    int t = (threadIdx.x >= off) ? sm[threadIdx.x - off] : 0;
    __syncthreads();
    sm[threadIdx.x] += t;
    __syncthreads();
  }
  if (i < V) rowptr[i + 1] = sm[threadIdx.x];
  if (threadIdx.x == 1023) bsum[blockIdx.x] = sm[1023];
}

__global__ __launch_bounds__(1024) void k_scan2(int* __restrict__ bsum, int nb) {
  __shared__ int sm[1024];
  int v = (threadIdx.x < nb) ? bsum[threadIdx.x] : 0;
  sm[threadIdx.x] = v;
  __syncthreads();
  for (int off = 1; off < 1024; off <<= 1) {
    int t = (threadIdx.x >= off) ? sm[threadIdx.x - off] : 0;
    __syncthreads();
    sm[threadIdx.x] += t;
    __syncthreads();
  }
  if (threadIdx.x < nb) bsum[threadIdx.x] = sm[threadIdx.x] - v;  // exclusive
}

__global__ __launch_bounds__(1024) void k_scan3(int* __restrict__ rowptr,
                                                const int* __restrict__ bsum,
                                                int* __restrict__ cursor, int V) {
  int i = blockIdx.x * 1024 + threadIdx.x;
  if (i < V) {
    int v = rowptr[i + 1] + bsum[blockIdx.x];
    rowptr[i + 1] = v;
    if (i + 1 < V) cursor[i + 1] = v;
  }
  if (i == 0) {
    rowptr[0] = 0;
    cursor[0] = 0;
  }
}

__global__ __launch_bounds__(256) void k_place(const int* __restrict__ src,
                                               const int* __restrict__ dst, int E,
                                               int* __restrict__ cursor,
                                               int* __restrict__ csr_src) {
  int e = blockIdx.x * 256 + threadIdx.x;
  if (e < E) {
    int d = dst[e];
    int slot = atomicAdd(&cursor[d], 1);
    csr_src[slot] = src[e];
  }
}

__global__ __launch_bounds__(256) void k_place_idx(const int* __restrict__ dst, int E,
                                                   int* __restrict__ cursor,
                                                   int* __restrict__ members,
                                                   int* __restrict__ clmem) {
  int e = blockIdx.x * 256 + threadIdx.x;
  if (e < E) {
    int d = dst[e];
    int slot = atomicAdd(&cursor[d], 1);
    members[slot] = e;
    clmem[slot] = d;
  }
}

// ---------------- one-block CSR build (tiny layers: V<=1536, E<=32K) --------
__global__ __launch_bounds__(1024) void k_csr_small(const int* __restrict__ src,
                                                    const int* __restrict__ dst,
                                                    int E, int V,
                                                    int* __restrict__ rowptr,
                                                    int* __restrict__ outp) {
  __shared__ int hist[1536];
  __shared__ int cur[1536];
  __shared__ int tmp[1024];
  int t = threadIdx.x;
  for (int i = t; i < V; i += 1024) hist[i] = 0;
  __syncthreads();
  for (int e = t; e < E; e += 1024) atomicAdd(&hist[dst[e]], 1);
  __syncthreads();
  int carry = 0;
  for (int base = 0; base < V; base += 1024) {
    int idx = base + t;
    int v = (idx < V) ? hist[idx] : 0;
    tmp[t] = v;
    __syncthreads();
    for (int off = 1; off < 1024; off <<= 1) {
      int a = (t >= off) ? tmp[t - off] : 0;
      __syncthreads();
      tmp[t] += a;
      __syncthreads();
    }
    if (idx < V) {
      int incl = tmp[t] + carry;
      rowptr[idx + 1] = incl;
      cur[idx] = incl - v;
    }
    carry += tmp[1023];
    __syncthreads();
  }
  if (t == 0) rowptr[0] = 0;
  __syncthreads();
  for (int e = t; e < E; e += 1024) {
    int slot = atomicAdd(&cur[dst[e]], 1);
    outp[slot] = src[e];
  }
}

// one-block pool CSR (pools 3/4: Vout<=1536)
__global__ __launch_bounds__(1024) void k_pool_csr_small(
    const float* __restrict__ pos, int prevCells, int Vin, int nx, int ny, int nt,
    int* __restrict__ cluster, int* __restrict__ rowptr, int* __restrict__ members,
    int* __restrict__ clmem) {
  __shared__ int hist[1536];
  __shared__ int cur[1536];
  __shared__ int tmp[1024];
  int V = 4 * nx * ny * nt;
  int t = threadIdx.x;
  for (int i = t; i < V; i += 1024) hist[i] = 0;
  __syncthreads();
  for (int n = t; n < Vin; n += 1024) {
    float px = pos[3 * n], py = pos[3 * n + 1], pz = pos[3 * n + 2];
    int b = n / prevCells;
    int ix = (int)floorf(px * nx);
    ix = ix < 0 ? 0 : (ix > nx - 1 ? nx - 1 : ix);
    int iy = (int)floorf(py * ny);
    iy = iy < 0 ? 0 : (iy > ny - 1 ? ny - 1 : iy);
    int it = (int)floorf(pz * nt);
    it = it < 0 ? 0 : (it > nt - 1 ? nt - 1 : it);
    int cl = ((b * nx + ix) * ny + iy) * nt + it;
    cluster[n] = cl;
    atomicAdd(&hist[cl], 1);
  }
  __syncthreads();
  int carry = 0;
  for (int base = 0; base < V; base += 1024) {
    int idx = base + t;
    int v = (idx < V) ? hist[idx] : 0;
    tmp[t] = v;
    __syncthreads();
    for (int off = 1; off < 1024; off <<= 1) {
      int a = (t >= off) ? tmp[t - off] : 0;
      __syncthreads();
      tmp[t] += a;
      __syncthreads();
    }
    if (idx < V) {
      int incl = tmp[t] + carry;
      rowptr[idx + 1] = incl;
      cur[idx] = incl - v;
    }
    carry += tmp[1023];
    __syncthreads();
  }
  if (t == 0) rowptr[0] = 0;
  __syncthreads();
  for (int n = t; n < Vin; n += 1024) {
    int cl = cluster[n];
    int slot = atomicAdd(&cur[cl], 1);
    members[slot] = n;
    clmem[slot] = cl;
  }
}

// ---------------- bucketed CSR build (large layers) ----------------
__global__ __launch_bounds__(256) void k_bhist(const int* __restrict__ dst, int E,
                                               int EPB, int NBLK, int NBUK,
                                               int* __restrict__ bhisto) {
  __shared__ int sm[1024];
  for (int b = threadIdx.x; b < NBUK; b += 256) sm[b] = 0;
  __syncthreads();
  int blk = blockIdx.x;
  int e0 = blk * EPB, e1 = min(e0 + EPB, E);
  for (int i = e0 + threadIdx.x; i < e1; i += 256) atomicAdd(&sm[dst[i] >> 9], 1);
  __syncthreads();
  for (int b = threadIdx.x; b < NBUK; b += 256) bhisto[b * NBLK + blk] = sm[b];
}

__global__ __launch_bounds__(256) void k_bplace(const int* __restrict__ payload,
                                                const int* __restrict__ dst, int E,
                                                int EPB, int NBLK, int NBUK,
                                                const int* __restrict__ bexcl,
                                                int2* __restrict__ ebuf) {
  __shared__ int cur[1024];
  int blk = blockIdx.x;
  for (int b = threadIdx.x; b < NBUK; b += 256) cur[b] = bexcl[b * NBLK + blk];
  __syncthreads();
  int e0 = blk * EPB, e1 = min(e0 + EPB, E);
  for (int i = e0 + threadIdx.x; i < e1; i += 256) {
    int d = dst[i];
    int slot = atomicAdd(&cur[d >> 9], 1);
    ebuf[slot] = make_int2(payload ? payload[i] : i, d);
  }
}

__global__ __launch_bounds__(256) void k_bcsr(const int2* __restrict__ ebuf,
                                              const int* __restrict__ bexcl, int E,
                                              int NBLK, int NBUK, int V,
                                              int* __restrict__ rowptr,
                                              int* __restrict__ outp) {
  __shared__ int sm[512];
  __shared__ int cur[512];
  int b = blockIdx.x;
  int t = threadIdx.x;
  int ebase = bexcl[b * NBLK];
  int eend = (b + 1 < NBUK) ? bexcl[(b + 1) * NBLK] : E;
  int dst0 = b << 9;
  sm[t] = 0;
  sm[t + 256] = 0;
  __syncthreads();
  for (int j = ebase + t; j < eend; j += 256) atomicAdd(&sm[ebuf[j].y - dst0], 1);
  __syncthreads();
  for (int off = 1; off < 512; off <<= 1) {
    int a0 = (t >= off) ? sm[t - off] : 0;
    int a1 = (t + 256 >= off) ? sm[t + 256 - off] : 0;
    __syncthreads();
    sm[t] += a0;
    sm[t + 256] += a1;
    __syncthreads();
  }
  if (b == 0 && t == 0) rowptr[0] = 0;
  int nd = V - dst0;
  if (nd > 512) nd = 512;
  for (int i = t; i < nd; i += 256) rowptr[dst0 + i + 1] = ebase + sm[i];
  cur[t] = ebase + ((t == 0) ? 0 : sm[t - 1]);
  cur[t + 256] = ebase + sm[t + 255];
  __syncthreads();
  for (int j = ebase + t; j < eend; j += 256) {
    int2 e = ebuf[j];
    int slot = atomicAdd(&cur[e.y - dst0], 1);
    outp[slot] = e.x;
  }
}

// ---------------- pos4 pack: (px,py,pz,x) ----------------
__global__ __launch_bounds__(256) void k_pack4(const float* __restrict__ pos,
                                               const float* __restrict__ x,
                                               float4* __restrict__ pos4, int V) {
  int n = blockIdx.x * 256 + threadIdx.x;
  if (n < V) pos4[n] = make_float4(pos[3 * n], pos[3 * n + 1], pos[3 * n + 2], x[n]);
}

// ---------------- L1 fused conv (corner-major, pos4) ----------------
__global__ __launch_bounds__(256) void k_conv1(const int* __restrict__ rowptr,
                                               const int* __restrict__ csr_src,
                                               const float4* __restrict__ pos4,
                                               const float* __restrict__ Wk,
                                               const float* __restrict__ R,
                                               const float* __restrict__ bias,
                                               float* __restrict__ out, int V,
                                               float inv2m) {
  constexpr int NZ = 24, NROW = 27;
  __shared__ float WL[NROW * 16];
  __shared__ float BL[16];
  __shared__ float zrow[4][32];
  int tid = threadIdx.x;
  for (int i = tid; i < NROW * 16; i += 256)
    WL[i] = (i < NZ * 16) ? Wk[i] : R[i - NZ * 16];
  if (tid < 16) BL[tid] = bias[tid];
  __syncthreads();
  int lane = tid & 63;
  int wv = tid >> 6;
  int u = lane & 7;  // corner index
  int n = blockIdx.x * 4 + wv;
  if (n >= V) return;
  int start = rowptr[n], end = rowptr[n + 1];
  float z0 = 0.f, z1 = 0.f, z2 = 0.f;
  float4 pn = pos4[n];
  for (int j0 = start; j0 < end; j0 += 8) {
    int j = j0 + (lane >> 3);
    bool valid = (j < end);
    int js = valid ? j : (end - 1);
    int s = csr_src[js];
    float4 ps = pos4[s];
    float p0 = fclamp01((pn.x - ps.x) * inv2m + 0.5f);
    float p1 = fclamp01((pn.y - ps.y) * inv2m + 0.5f);
    float p2 = fclamp01((pn.z - ps.z) * inv2m + 0.5f);
    float b = ((u & 1) ? p0 : (1.f - p0)) * ((u & 2) ? p1 : (1.f - p1)) *
              ((u & 4) ? p2 : (1.f - p2)) * (valid ? 1.f : 0.f);
    z0 += b * ps.w;  // k=0: x_src
    z1 += b * ps.x;  // k=1: src px
    z2 += b * ps.y;  // k=2: src py
  }
#pragma unroll
  for (int m = 8; m < 64; m <<= 1) {
    z0 += __shfl_xor(z0, m);
    z1 += __shfl_xor(z1, m);
    z2 += __shfl_xor(z2, m);
  }
  float inv = 1.f / fmaxf((float)(end - start), 1.f);
  if (lane < 8) {  // z entry idx = corner*3 + k (matches W row order)
    zrow[wv][u * 3 + 0] = z0 * inv;
    zrow[wv][u * 3 + 1] = z1 * inv;
    zrow[wv][u * 3 + 2] = z2 * inv;
  }
  if (lane == 8) {
    zrow[wv][24] = pn.w;
    zrow[wv][25] = pn.x;
    zrow[wv][26] = pn.y;
  }
  // wave-local LDS: DS ops from one wave execute in order; no barrier needed.
  if (lane < 16) {
    float acc = BL[lane];
#pragma unroll
    for (int j = 0; j < NROW; j++) acc += zrow[wv][j] * WL[j * 16 + lane];
    out[(size_t)n * 16 + lane] = fmaxf(acc, 0.f);
  }
}

// ---------------- gather: EPG edges in parallel per wave ----------------
template <int CIN, int EPG>
__global__ __launch_bounds__(256) void k_gather(const int* __restrict__ rowptr,
                                                const int* __restrict__ csr_src,
                                                const float* __restrict__ hin,
                                                const float* __restrict__ pos,
                                                float* __restrict__ Z, int nodeBase,
                                                int nodeEnd, float inv2m) {
  constexpr int CH = CIN - 2;
  constexpr int NZ = 8 * CIN;
  constexpr int ROW = 9 * CIN;
  constexpr int LPE = 64 / EPG;
  constexpr int NE = (NZ + LPE - 1) / LPE;
  int lane = threadIdx.x & 63;
  int u = lane & (LPE - 1);
  int g = lane / LPE;
  int n = nodeBase + blockIdx.x * 4 + (threadIdx.x >> 6);
  if (n >= nodeEnd) return;
  int start = rowptr[n], end = rowptr[n + 1];
  float z[NE];
#pragma unroll
  for (int i = 0; i < NE; i++) z[i] = 0.f;
  float dx = pos[3 * n], dy = pos[3 * n + 1], dz = pos[3 * n + 2];
  for (int j0 = start; j0 < end; j0 += EPG) {
    int j = j0 + g;
    bool valid = (j < end);
    int js = valid ? j : (end - 1);
    int s = csr_src[js];
    float sx = pos[3 * s], sy = pos[3 * s + 1], sz = pos[3 * s + 2];
    float p0 = fclamp01((dx - sx) * inv2m + 0.5f);
    float p1 = fclamp01((dy - sy) * inv2m + 0.5f);
    float p2 = fclamp01((dz - sz) * inv2m + 0.5f);
    float q0 = 1.f - p0, q1 = 1.f - p1, q2 = 1.f - p2;
    float vm = valid ? 1.f : 0.f;
#pragma unroll
    for (int i = 0; i < NE; i++) {
      int idx = u + LPE * i;
      if (idx < NZ) {
        int ss = idx / CIN;
        int k = idx - ss * CIN;
        float b = ((ss & 1) ? p0 : q0) * ((ss & 2) ? p1 : q1) *
                  ((ss & 4) ? p2 : q2) * vm;
        float xv = (k < CH) ? hin[(size_t)s * CH + k] : ((k == CH) ? sx : sy);
        z[i] += b * xv;
      }
    }
  }
  if (EPG > 1) {
#pragma unroll
    for (int m = LPE; m < 64; m <<= 1) {
#pragma unroll
      for (int i = 0; i < NE; i++) z[i] += __shfl_xor(z[i], m);
    }
  }
  float inv = 1.f / fmaxf((float)(end - start), 1.f);
  float* zr = &Z[(size_t)(n - nodeBase) * ROW];
  if (lane < LPE) {
#pragma unroll
    for (int i = 0; i < NE; i++) {
      int idx = u + LPE * i;
      if (idx < NZ) zr[idx] = z[i] * inv;
    }
  }
  for (int k = lane; k < CIN; k += 64) {
    zr[NZ + k] = (k < CH) ? hin[(size_t)n * CH + k] : ((k == CH) ? dx : dy);
  }
}

// ------- mid GEMM (L2/L3): thread=(cout,row), NB nodes/block, W from L2 -----
template <int CIN, int COUT, int NB>
__global__ __launch_bounds__(256) void k_gemm_mid(
    const float* __restrict__ Z, const float* __restrict__ Wk,
    const float* __restrict__ R, const float* __restrict__ bias,
    float* __restrict__ out, int nodeBase, int nodeCount) {
  constexpr int NZ = 8 * CIN, K = 9 * CIN;
  constexpr int ROWS = 256 / COUT;
  constexpr int NPT = NB / ROWS;
  constexpr int KC = 64;
  __shared__ float ZL[NB][KC];
  int c = threadIdx.x & (COUT - 1);
  int r = threadIdx.x / COUT;
  int n0 = blockIdx.x * NB;
  float acc[NPT];
#pragma unroll
  for (int t = 0; t < NPT; t++) acc[t] = 0.f;
  for (int k0 = 0; k0 < K; k0 += KC) {
    __syncthreads();
    for (int i = threadIdx.x; i < NB * KC; i += 256) {
      int nn = i / KC, kk = i - nn * KC;
      int gk = k0 + kk;
      ZL[nn][kk] =
          (n0 + nn < nodeCount && gk < K) ? Z[(size_t)(n0 + nn) * K + gk] : 0.f;
    }
    __syncthreads();
    int kc = (K - k0 < KC) ? (K - k0) : KC;
#pragma unroll 4
    for (int kk = 0; kk < kc; kk++) {
      int gk = k0 + kk;
      float w = (gk < NZ) ? Wk[(size_t)gk * COUT + c]
                          : R[(size_t)(gk - NZ) * COUT + c];
#pragma unroll
      for (int t = 0; t < NPT; t++) acc[t] += ZL[r * NPT + t][kk] * w;
    }
  }
#pragma unroll
  for (int t = 0; t < NPT; t++) {
    int node = n0 + r * NPT + t;
    if (node < nodeCount)
      out[(size_t)(nodeBase + node) * COUT + c] = fmaxf(acc[t] + bias[c], 0.f);
  }
}

// ---------------- skinny GEMM (small V, big K) ----------------
template <int CIN, int COUT>
__global__ __launch_bounds__(256) void k_gemm_skinny(
    const float* __restrict__ Z, const float* __restrict__ Wk,
    const float* __restrict__ R, const float* __restrict__ bias,
    float* __restrict__ out, int nodeCount) {
  constexpr int NZ = 8 * CIN, K = 9 * CIN;
  constexpr int NPB = 256 / COUT;
  constexpr int KC = 64;
  __shared__ float ZL[NPB][KC];
  int c = threadIdx.x & (COUT - 1);
  int ln = threadIdx.x / COUT;
  int n0 = blockIdx.x * NPB;
  float acc = 0.f;
  for (int k0 = 0; k0 < K; k0 += KC) {
    __syncthreads();
    for (int i = threadIdx.x; i < NPB * KC; i += 256) {
      int nn = i / KC, kk = i - (i / KC) * KC;
      int gk = k0 + kk;
      ZL[nn][kk] =
          (n0 + nn < nodeCount && gk < K) ? Z[(size_t)(n0 + nn) * K + gk] : 0.f;
    }
    __syncthreads();
    int kmax = (K - k0 < KC) ? (K - k0) : KC;
#pragma unroll 8
    for (int kk = 0; kk < kmax; kk++) {
      int gk = k0 + kk;
      float w = (gk < NZ) ? Wk[(size_t)gk * COUT + c]
                          : R[(size_t)(gk - NZ) * COUT + c];
      acc += ZL[ln][kk] * w;
    }
  }
  int n = n0 + ln;
  if (n < nodeCount) out[(size_t)n * COUT + c] = fmaxf(acc + bias[c], 0.f);
}

// ---------------- voxel pooling ----------------
__global__ __launch_bounds__(256) void k_cluster4(const float4* __restrict__ pos4,
                                                  const int* __restrict__ batch,
                                                  int Vin, int nx, int ny, int nt,
                                                  int* __restrict__ cluster) {
  int n = blockIdx.x * 256 + threadIdx.x;
  if (n >= Vin) return;
  float4 p = pos4[n];
  int b = batch[n];
  int ix = (int)floorf(p.x * nx);
  ix = ix < 0 ? 0 : (ix > nx - 1 ? nx - 1 : ix);
  int iy = (int)floorf(p.y * ny);
  iy = iy < 0 ? 0 : (iy > ny - 1 ? ny - 1 : iy);
  int it = (int)floorf(p.z * nt);
  it = it < 0 ? 0 : (it > nt - 1 ? nt - 1 : it);
  cluster[n] = ((b * nx + ix) * ny + iy) * nt + it;
}

__global__ __launch_bounds__(256) void k_cluster_count(
    const float* __restrict__ pos, int prevCells, int Vin, int nx, int ny, int nt,
    int* __restrict__ cluster, int* __restrict__ cnt) {
  int n = blockIdx.x * 256 + threadIdx.x;
  if (n >= Vin) return;
  float px = pos[3 * n], py = pos[3 * n + 1], pz = pos[3 * n + 2];
  int b = n / prevCells;
  int ix = (int)floorf(px * nx);
  ix = ix < 0 ? 0 : (ix > nx - 1 ? nx - 1 : ix);
  int iy = (int)floorf(py * ny);
  iy = iy < 0 ? 0 : (iy > ny - 1 ? ny - 1 : iy);
  int it = (int)floorf(pz * nt);
  it = it < 0 ? 0 : (it > nt - 1 ? nt - 1 : it);
  int cl = ((b * nx + ix) * ny + iy) * nt + it;
  cluster[n] = cl;
  atomicAdd(&cnt[cl], 1);
}

// pool1 (balanced): thread = (cluster, channel), serial member loop.
template <int C, bool MAXP>
__global__ __launch_bounds__(256) void k_pool_gather(
    const int* __restrict__ rowptr, const int* __restrict__ members,
    const float* __restrict__ h, const float* __restrict__ pos,
    float* __restrict__ featOut, float* __restrict__ posOut, int Vout) {
  int idx = blockIdx.x * 256 + threadIdx.x;
  int cl = idx / C, ch = idx - (idx / C) * C;
  if (cl >= Vout) return;
  int start = rowptr[cl], end = rowptr[cl + 1];
  float acc = 0.f, ps = 0.f;
  for (int j = start; j < end; j++) {
    int m = members[j];
    float v = h[(size_t)m * C + ch];
    acc = MAXP ? fmaxf(acc, v) : (acc + v);
    if (ch < 3) ps += pos[3 * m + ch];
  }
  float invc = 1.f / fmaxf((float)(end - start), 1.f);
  featOut[(size_t)cl * C + ch] = MAXP ? acc : acc * invc;
  if (ch < 3) posOut[3 * cl + ch] = ps * invc;
}

// pools 2-4: member-parallel strips, segmented boundary-flush atomics.
template <int C, bool MAXP>
__global__ __launch_bounds__(256) void k_pool_strip(
    const int* __restrict__ members, const int* __restrict__ clmem,
    const float* __restrict__ h, const float* __restrict__ pos,
    float* __restrict__ feat, float* __restrict__ psum, int Vin) {
  constexpr int CPB = (C < 64) ? C : 64;
  constexpr int MPW = 64 / CPB;
  constexpr int STRIP = 16;
  int lane = threadIdx.x & 63;
  int wave = (blockIdx.x * 256 + threadIdx.x) >> 6;
  int grp = lane / CPB;
  int chp = lane - grp * CPB;
  int ch = chp + CPB * blockIdx.y;
  int base = wave * (STRIP * MPW) + grp * STRIP;
  bool doPos = (blockIdx.y == 0) && (chp < 3);
  float acc = 0.f, pacc = 0.f;
  int cur = -1;
#pragma unroll
  for (int k = 0; k < STRIP; k++) {
    int j = base + k;
    if (j < Vin) {
      int cl = clmem[j];
      int m = members[j];
      float v = h[(size_t)m * C + ch];
      float pv = doPos ? pos[3 * m + chp] : 0.f;
      if (cl != cur) {
        if (cur >= 0) {
          if (MAXP)
            atomicMax((unsigned int*)&feat[(size_t)cur * C + ch],
                      __float_as_uint(acc));
          else
            atomicAdd(&feat[(size_t)cur * C + ch], acc);
          if (doPos) atomicAdd(&psum[3 * cur + chp], pacc);
        }
        acc = v;
        pacc = pv;
        cur = cl;
      } else {
        acc = MAXP ? fmaxf(acc, v) : acc + v;
        pacc += pv;
      }
    }
  }
  if (cur >= 0) {
    if (MAXP)
      atomicMax((unsigned int*)&feat[(size_t)cur * C + ch], __float_as_uint(acc));
    else
      atomicAdd(&feat[(size_t)cur * C + ch], acc);
    if (doPos) atomicAdd(&psum[3 * cur + chp], pacc);
  }
}

template <int C, bool MEANP>
__global__ __launch_bounds__(256) void k_pool_fin(const int* __restrict__ rowptr,
                                                  const float* __restrict__ psum,
                                                  float* __restrict__ feat,
                                                  float* __restrict__ posOut,
                                                  int Vout) {
  int v = blockIdx.x * 256 + threadIdx.x;
  if (v >= Vout) return;
  float invc = 1.f / fmaxf((float)(rowptr[v + 1] - rowptr[v]), 1.f);
  posOut[3 * v] = psum[3 * v] * invc;
  posOut[3 * v + 1] = psum[3 * v + 1] * invc;
  posOut[3 * v + 2] = psum[3 * v + 2] * invc;
  if (MEANP) {
    for (int i = 0; i < C; i++) feat[(size_t)v * C + i] *= invc;
  }
}

extern "C" void kernel_launch(void* const* d_in, const int* in_sizes, int n_in,
                              void* d_out, int out_size, void* d_ws, size_t ws_size,
                              hipStream_t stream) {
  (void)in_sizes; (void)n_in; (void)out_size; (void)ws_size;
  const float* x = (const float*)d_in[0];
  const float* pos0 = (const float*)d_in[1];
  const int* batch = (const int*)d_in[2];
  const int* e0 = (const int*)d_in[3];
  const int* e1 = (const int*)d_in[4];
  const int* e2 = (const int*)d_in[5];
  const int* e3 = (const int*)d_in[6];
  const int* e4 = (const int*)d_in[7];
  const float* W1 = (const float*)d_in[8];
  const float* R1 = (const float*)d_in[9];
  const float* b1 = (const float*)d_in[10];
  const float* W2 = (const float*)d_in[11];
  const float* R2 = (const float*)d_in[12];
  const float* b2 = (const float*)d_in[13];
  const float* W3 = (const float*)d_in[14];
  const float* R3 = (const float*)d_in[15];
  const float* b3 = (const float*)d_in[16];
  const float* W4 = (const float*)d_in[17];
  const float* R4 = (const float*)d_in[18];
  const float* b4 = (const float*)d_in[19];
  const float* W5 = (const float*)d_in[20];
  const float* R5 = (const float*)d_in[21];
  const float* b5 = (const float*)d_in[22];

  float* out3 = (float*)d_out;            // 1536*128
  float* out5 = (float*)d_out + 196608;   // 192*128

  char* w = (char*)d_ws;
  auto carve = [&](size_t bytes) {
    char* p = w;
    w += (bytes + 255) & ~(size_t)255;
    return p;
  };
  int* cnt = (int*)carve(300001ull * 4);     // also bhisto [bucket][block]
  int* rowptr = (int*)carve(300001ull * 4);  // also scan tmp
  int* cursor = (int*)carve(300001ull * 4);  // also bexcl
  int* bsum = (int*)carve(1024 * 4);
  int* csr = (int*)carve(3600000ull * 4);
  int* cluster = (int*)carve(300000ull * 4);
  int* members = (int*)carve(300000ull * 4);
  int* clmem = (int*)carve(300000ull * 4);
  float* psum = (float*)carve(98304ull * 3 * 4);
  float4* pos4 = (float4*)carve(300000ull * 16);
  float* Zbuf = (float*)carve(8100000ull * 4);   // L2/L3 Z; also ebuf
  float* hA = (float*)carve(6291456ull * 4);     // conv outputs (max 98304*64)
  float* hB = (float*)carve(1572864ull * 4);     // pooled feats (max 98304*16)
  float* posA = (float*)carve(294912ull * 4);    // 98304*3
  float* posB = (float*)carve(36864ull * 4);     // 12288*3
  int2* ebuf = (int2*)Zbuf;                      // 3.6M*8B <= 32.4MB

  auto scan_rowptr = [&](int V) {  // cursor <- exclusive scan of cnt
    int nb = (V + 1023) / 1024;
    k_scan1<<<nb, 1024, 0, stream>>>(cnt, V, rowptr, bsum);
    k_scan2<<<1, 1024, 0, stream>>>(bsum, nb);
    k_scan3<<<nb, 1024, 0, stream>>>(rowptr, bsum, cursor, V);
  };

  auto csr_build = [&](const int* e, int E, int V) {
    hipMemsetAsync(cnt, 0, (size_t)V * 4, stream);
    k_count<<<(E + 255) / 256, 256, 0, stream>>>(e + E, E, cnt);
    scan_rowptr(V);
    k_place<<<(E + 255) / 256, 256, 0, stream>>>(e, e + E, E, cursor, csr);
  };

  auto csr_build_bucketed = [&](const int* payload, const int* dstArr, int E, int V,
                                int* outp) {
    int NBUK = (V + 511) >> 9;
    int EPB = 16384;
    int NBLK = (E + EPB - 1) / EPB;
    k_bhist<<<NBLK, 256, 0, stream>>>(dstArr, E, EPB, NBLK, NBUK, cnt);
    scan_rowptr(NBUK * NBLK);
    k_bplace<<<NBLK, 256, 0, stream>>>(payload, dstArr, E, EPB, NBLK, NBUK, cursor,
                                       ebuf);
    k_bcsr<<<NBUK, 256, 0, stream>>>(ebuf, cursor, E, NBLK, NBUK, V, rowptr, outp);
  };

  // ---------- Layer 1: V=300000, E=3600000, CIN=3, COUT=16 (fused) ----------
  k_pack4<<<(300000 + 255) / 256, 256, 0, stream>>>(pos0, x, pos4, 300000);
  csr_build_bucketed(e0, e0 + 3600000, 3600000, 300000, csr);
  k_conv1<<<(300000 + 3) / 4, 256, 0, stream>>>(rowptr, csr, pos4, W1, R1, b1, hA,
                                                300000, 20.0f);
  // pool1 (max) -> 98304, grid (64,48,8): bucketed members + balanced gather
  k_cluster4<<<(300000 + 255) / 256, 256, 0, stream>>>(pos4, batch, 300000, 64, 48,
                                                       8, cluster);
  csr_build_bucketed(nullptr, cluster, 300000, 98304, members);
  k_pool_gather<16, true><<<(98304 * 16 + 255) / 256, 256, 0, stream>>>(
      rowptr, members, hA, pos0, hB, posA, 98304);

  // ---------- Layer 2: V=98304, E=786432, CIN=18, COUT=64 (2 chunks) ----------
  csr_build_bucketed(e1, e1 + 786432, 786432, 98304, csr);
  for (int c = 0; c < 2; c++) {
    int base = c * 49152, n = 49152;
    k_gather<18, 2><<<(n + 3) / 4, 256, 0, stream>>>(rowptr, csr, hB, posA, Zbuf,
                                                     base, base + n, 10.0f);
    k_gemm_mid<18, 64, 16><<<(n + 15) / 16, 256, 0, stream>>>(Zbuf, W2, R2, b2, hA,
                                                              base, n);
  }
  // pool2 (max) -> 12288: strip (skewed: empty-voxel pos=0 hot cluster)
  {
    hipMemsetAsync(cnt, 0, 12288ull * 4, stream);
    k_cluster_count<<<(98304 + 255) / 256, 256, 0, stream>>>(posA, 24576, 98304, 32,
                                                             24, 4, cluster, cnt);
    scan_rowptr(12288);
    k_place_idx<<<(98304 + 255) / 256, 256, 0, stream>>>(cluster, 98304, cursor,
                                                         members, clmem);
  }
  hipMemsetAsync(hB, 0, 12288ull * 64 * 4, stream);
  hipMemsetAsync(psum, 0, 12288ull * 3 * 4, stream);
  k_pool_strip<64, true><<<dim3(1536, 1), 256, 0, stream>>>(members, clmem, hA, posA,
                                                            hB, psum, 98304);
  k_pool_fin<64, false><<<(12288 + 255) / 256, 256, 0, stream>>>(rowptr, psum, hB,
                                                                 posB, 12288);

  // ---------- Layer 3: V=12288, E=196608, CIN=66, COUT=128 ----------
  csr_build(e2, 196608, 12288);
  k_gather<66, 2><<<(12288 + 3) / 4, 256, 0, stream>>>(rowptr, csr, hB, posB, Zbuf,
                                                       0, 12288, 6.0f);
  k_gemm_mid<66, 128, 8><<<(12288 + 7) / 8, 256, 0, stream>>>(Zbuf, W3, R3, b3, hA,
                                                              0, 12288);
  // pool3 (max) -> 1536: one-block CSR + strip
  k_pool_csr_small<<<1, 1024, 0, stream>>>(posB, 3072, 12288, 16, 12, 2, cluster,
                                           rowptr, members, clmem);
  hipMemsetAsync(hB, 0, 1536ull * 128 * 4, stream);
  hipMemsetAsync(psum, 0, 1536ull * 3 * 4, stream);
  k_pool_strip<128, true><<<dim3(192, 2), 256, 0, stream>>>(members, clmem, hA, posB,
                                                            hB, psum, 12288);
  k_pool_fin<128, false><<<(1536 + 255) / 256, 256, 0, stream>>>(rowptr, psum, hB,
                                                                 posA, 1536);

  // ---------- Layer 4: V=1536, E=24576, CIN=130, COUT=128 -> out3 ----------
  k_csr_small<<<1, 1024, 0, stream>>>(e3, e3 + 24576, 24576, 1536, rowptr, csr);
  k_gather<130, 1><<<(1536 + 3) / 4, 256, 0, stream>>>(rowptr, csr, hB, posA, Zbuf,
                                                       0, 1536, 3.0f);
  k_gemm_skinny<130, 128><<<768, 256, 0, stream>>>(Zbuf, W4, R4, b4, out3, 1536);
  // pool4 (mean) -> 192: one-block CSR + strip
  k_pool_csr_small<<<1, 1024, 0, stream>>>(posA, 384, 1536, 8, 6, 1, cluster, rowptr,
                                           members, clmem);
  hipMemsetAsync(hB, 0, 192ull * 128 * 4, stream);
  hipMemsetAsync(psum, 0, 192ull * 3 * 4, stream);
  k_pool_strip<128, false><<<dim3(24, 2), 256, 0, stream>>>(members, clmem, out3,
                                                            posA, hB, psum, 1536);
  k_pool_fin<128, true><<<1, 256, 0, stream>>>(rowptr, psum, hB, posB, 192);

  // ---------- Layer 5: V=192, E=3072, CIN=130, COUT=128 -> out5 ----------
  k_csr_small<<<1, 1024, 0, stream>>>(e4, e4 + 3072, 3072, 192, rowptr, csr);
  k_gather<130, 1><<<(192 + 3) / 4, 256, 0, stream>>>(rowptr, csr, hB, posB, Zbuf, 0,
                                                      192, 1.5f);
  k_gemm_skinny<130, 128><<<96, 256, 0, stream>>>(Zbuf, W5, R5, b5, out5, 192);
}